// Round 11
// baseline (391.014 us; speedup 1.0000x reference)
//
#include <hip/hip_runtime.h>
#include <hip/hip_bf16.h>
#include <math.h>

#define T_IN 98304
#define SS 128
#define NBATCH 2
#define NN 256          // NBATCH*SS
#define C1 256
#define C2 512
#define C3 7168
#define NCBK 14
#define DIMV 512
#define VOC 1024
#define TOUT 97537
#define HOP 768

// ws layout (float offsets). Harness allocates ~280 MB ws (fill WRITE_SIZE
// = 286720 KB); fresh space beyond 11880720 confirmed usable (rounds 7-9
// used up to 124 MB). This round uses up to ~163 MB.
#define OFF_CBN    0L          // 14336
#define OFF_AB1    14336L      // 512
#define OFF_AB2    14848L      // 256
#define OFF_CCONST 15104L      // 16
#define OFF_H2C    15120L      // 131072   (n*512+ic), n=b*128+s
// h2xp: fragment-packed bf16 [16 nt][48 kt][512] per plane (196608 fl each)
#define OFF_H2XH   146192L     // ends 342800
#define OFF_H2XL   342800L     // ends 539408
// h3p: fragment-packed bf16 (B-operand layout for gemm_scores)
#define OFF_H3H    539408L     // ends 1456912
#define OFF_H3L    1456912L    // ends 2374416
// X1p fragment-packed bf16 [16 nt][40 kt][512] (163840 fl each)
#define OFF_X1H    2374416L    // ends 2538256
#define OFF_X1L    2538256L    // ends 2702096
// Xp hi/lo fragment-packed [144 nt][80 kt][512] per plane (2949120 fl each)
// OVERLAP h3p/X1 (dead after gemm_scores; k_x2 launches after gemm_a1).
#define OFF_XH     539408L     // ends 3488528
#define OFF_XL     3488528L    // ends 6437648
#define OFF_CODES  9714448L    // 3584 ints
#define OFF_QBF    9718032L    // 917504 fl (bf16 fragment-packed [16 nt][224 kt][512])
#define OFF_A1RAW  10635536L   // 655360   ((n*5+j)*512 + c)  pre-bias/relu
#define OFF_A2ACT  11290896L   // 589824   ((n*9+u)*256 + o)  post-relu
// ---- fresh space (no aliasing) ----
#define OFF_CBPH   11880720L   // ends 15550736
#define OFF_CBPL   15550736L   // ends 19220752
#define OFF_EW3PH  19220752L   // ends 24725776
#define OFF_EW3PL  24725776L   // ends 30230800
#define OFF_EW2PH  30230800L   // ends 30558480
#define OFF_EW2PL  30558480L   // ends 30886160
#define OFF_PVAL   30886160L   // ends 30943504
#define OFF_PIDX   30943504L   // ends 31000848
#define OFF_DW1P   31000848L   // ends 40175888  (bf16 [160 mt][224 kt][512])
#define OFF_DW2PH  40175888L   // ends 40503568  (bf16 [16 mt][80 kt][512])
#define OFF_DW2PL  40503568L   // ends 40831248
// total ~163.3 MB

typedef __attribute__((ext_vector_type(8))) short short8;
typedef __attribute__((ext_vector_type(4))) float f32x4;

static __device__ inline ushort f2bf(float x) {
  __hip_bfloat16 h = __float2bfloat16(x);
  return *reinterpret_cast<ushort*>(&h);
}

// exact 2-term split: x = hi + lo + O(2^-16 |x|); truncation split, residual exact
static __device__ inline void split8(const float4 x0, const float4 x1,
                                     short8& h, short8& l) {
  float xs[8] = {x0.x, x0.y, x0.z, x0.w, x1.x, x1.y, x1.z, x1.w};
  #pragma unroll
  for (int e = 0; e < 8; ++e) {
    uint b = __float_as_uint(xs[e]);
    h[e] = (short)(b >> 16);
    float r = xs[e] - __uint_as_float(b & 0xffff0000u);
    l[e] = (short)(__float_as_uint(r) >> 16);
  }
}

// ---------------- ONE pack kernel for all weights (was 5 kernels) ----------------
// Sections by blockIdx.x:
//  [0,896)      : cb -> cbp hi/lo + row norms (zmt = bid)
//  [896,1216)   : ew2 -> ew2p
//  [1216,6592)  : ew3 -> ew3p
//  [6592,6912)  : dw2 -> dw2p
//  [6912,11392) : dw1 -> dw1p (LDS transpose, kb = idx/40, mb = idx%40)
__global__ __launch_bounds__(256) void k_packw(const float* __restrict__ cb,
    const float* __restrict__ ew2, const float* __restrict__ ew3,
    const float* __restrict__ dw2, const float* __restrict__ dw1,
    ushort* __restrict__ cbph, ushort* __restrict__ cbpl, float* __restrict__ cbn,
    ushort* __restrict__ ew2ph, ushort* __restrict__ ew2pl,
    ushort* __restrict__ ew3ph, ushort* __restrict__ ew3pl,
    ushort* __restrict__ dw2ph, ushort* __restrict__ dw2pl,
    ushort* __restrict__ dw1p) {
  __shared__ __align__(16) ushort T[64 * 72];
  __shared__ float red[256];
  const int bid = blockIdx.x;
  const int t = threadIdx.x;
  if (bid < 896) {
    // ---- cbp + norms ----
    int zmt = bid;
    int lane = t & 63, fg = t >> 6;
    int quad = lane >> 4, l15 = lane & 15;
    int row = zmt * 16 + l15;
    float ss = 0.f;
    #pragma unroll
    for (int h = 0; h < 4; ++h) {
      int kt = fg * 4 + h;
      int k = kt * 32 + quad * 8;
      const float* s = cb + (long)row * DIMV + k;
      float4 x0 = *(const float4*)s;
      float4 x1 = *(const float4*)(s + 4);
      short8 hh, ll;
      split8(x0, x1, hh, ll);
      long off = ((long)zmt * 16 + kt) * 512 + lane * 8;
      *(short8*)(cbph + off) = hh;
      *(short8*)(cbpl + off) = ll;
      ss += x0.x*x0.x + x0.y*x0.y + x0.z*x0.z + x0.w*x0.w
          + x1.x*x1.x + x1.y*x1.y + x1.z*x1.z + x1.w*x1.w;
    }
    red[t] = ss;
    __syncthreads();
    if (t < 16) {
      float s = 0.f;
      #pragma unroll
      for (int g = 0; g < 16; ++g) s += red[t + g * 16];
      cbn[zmt * 16 + t] = s;
    }
  } else if (bid < 1216) {
    // ---- ew2p ----
    int o8 = (bid - 896) * 256 + t;            // < 81920
    int frag = o8 >> 6, lane = o8 & 63;
    int quad = lane >> 4, l15 = lane & 15;
    int mt = frag / 40, kt = frag - mt * 40;
    const float* s = ew2 + (long)(mt * 16 + l15) * 1280 + kt * 32 + quad * 8;
    float4 x0 = *(const float4*)s;
    float4 x1 = *(const float4*)(s + 4);
    short8 h, l;
    split8(x0, x1, h, l);
    long off = (long)o8 * 8;
    *(short8*)(ew2ph + off) = h;
    *(short8*)(ew2pl + off) = l;
  } else if (bid < 6592) {
    // ---- ew3p ----
    int o8 = (bid - 1216) * 256 + t;           // < 1376256
    int frag = o8 >> 6, lane = o8 & 63;
    int quad = lane >> 4, l15 = lane & 15;
    int mtL = frag / 48, kt = frag - mtL * 48;
    const float* s = ew3 + (long)(mtL * 16 + l15) * 1536 + kt * 32 + quad * 8;
    float4 x0 = *(const float4*)s;
    float4 x1 = *(const float4*)(s + 4);
    short8 h, l;
    split8(x0, x1, h, l);
    long off = (long)o8 * 8;
    *(short8*)(ew3ph + off) = h;
    *(short8*)(ew3pl + off) = l;
  } else if (bid < 6912) {
    // ---- dw2p ----
    int o8 = (bid - 6592) * 256 + t;           // < 81920
    int frag = o8 >> 6, lane = o8 & 63;
    int quad = lane >> 4, l15 = lane & 15;
    int mt = frag / 80, kt = frag - mt * 80;
    const float* s = dw2 + (long)(mt * 16 + l15) * 2560 + kt * 32 + quad * 8;
    float4 x0 = *(const float4*)s;
    float4 x1 = *(const float4*)(s + 4);
    short8 h, l;
    split8(x0, x1, h, l);
    long off = (long)o8 * 8;
    *(short8*)(dw2ph + off) = h;
    *(short8*)(dw2pl + off) = l;
  } else {
    // ---- dw1t: [7168][2560] fp32 -> fragment-packed bf16 ----
    int idx = bid - 6912;                      // < 4480
    int kb = idx / 40, mb = idx - kb * 40;
    int k0 = kb * 64, m0 = mb * 64;
    int kk = t >> 2, mj = (t & 3) * 16;
    const float* src = dw1 + (long)(k0 + kk) * 2560 + m0 + mj;
    float x[16];
    *(float4*)&x[0]  = *(const float4*)(src);
    *(float4*)&x[4]  = *(const float4*)(src + 4);
    *(float4*)&x[8]  = *(const float4*)(src + 8);
    *(float4*)&x[12] = *(const float4*)(src + 12);
    #pragma unroll
    for (int l = 0; l < 16; ++l)
      T[(mj + l) * 72 + kk] = f2bf(x[l]);
    __syncthreads();
    int mo = t >> 2, kc = (t & 3) * 16;
    const int m = m0 + mo;
    const int mt = m >> 4, l15 = m & 15;
    #pragma unroll
    for (int h = 0; h < 2; ++h) {
      const int kk0 = kc + h * 8;
      const int kglob = k0 + kk0;
      const int kt = kglob >> 5;
      const int quad = (kglob >> 3) & 3;
      uint4 u = *(const uint4*)&T[mo * 72 + kk0];
      *(uint4*)(dw1p + ((long)(mt * 224 + kt)) * 512 + (quad * 16 + l15) * 8) = u;
    }
  }
}

// ---------------- prep A: ab1 = relu(db1); ab2[o] = relu(db2[o]+sum_c W(o,c)*ab1[c])
__global__ __launch_bounds__(256) void k_prep_ab2(const float* __restrict__ db1,
    const float* __restrict__ dw2, const float* __restrict__ db2,
    float* __restrict__ ab1, float* __restrict__ ab2) {
  __shared__ float red[256];
  int o = blockIdx.x, t = threadIdx.x;
  if (o == 0) { ab1[t] = fmaxf(db1[t], 0.f); ab1[t + 256] = fmaxf(db1[t + 256], 0.f); }
  const float* wp = dw2 + (long)o * C2 * 5;
  float acc = 0.f;
  #pragma unroll
  for (int h = 0; h < 2; ++h) {
    int c = t + h * 256;
    const float* p = wp + c * 5;
    float wsum = p[0] + p[1] + p[2] + p[3] + p[4];
    acc = fmaf(wsum, fmaxf(db1[c], 0.f), acc);
  }
  red[t] = acc;
  __syncthreads();
  for (int off = 128; off; off >>= 1) {
    if (t < off) red[t] += red[t + off];
    __syncthreads();
  }
  if (t == 0) ab2[o] = fmaxf(red[0] + db2[o], 0.f);
}

// ---------------- prep B: cconst = tanh(db3 + sum_o (sum_j dw3[o][j]) * ab2[o]) ----
__global__ __launch_bounds__(256) void k_prep_c(const float* __restrict__ dw3,
    const float* __restrict__ db3, const float* __restrict__ ab2,
    float* __restrict__ cconst) {
  __shared__ float red[256];
  int t = threadIdx.x;
  float wsum3 = 0.f;
  #pragma unroll
  for (int j = 0; j < 7; ++j) wsum3 += dw3[t*7+j];
  red[t] = wsum3 * ab2[t];
  __syncthreads();
  for (int off = 128; off; off >>= 1) {
    if (t < off) red[t] += red[t + off];
    __syncthreads();
  }
  if (t == 0) cconst[0] = tanhf(red[0] + db3[0]);
}

// ---------------- encoder conv1 (k7,p3) at the 5 cols conv2 needs ----------------
// Output written fragment-packed: X1p[(nt*40+kt)*512 + (quadk*16 + n&15)*8 + k&7]
__global__ __launch_bounds__(256) void k_enc1(const float* __restrict__ audio,
    const float* __restrict__ ew1, const float* __restrict__ eb1,
    ushort* __restrict__ X1h, ushort* __restrict__ X1l) {
  int n = blockIdx.x, ic = threadIdx.x;
  int b = n >> 7, s = n & 127;
  const float* ap = audio + (long)b * T_IN;
  int base = HOP * s - 5;           // audio idx for window pos 0
  float a[11];
  #pragma unroll
  for (int w = 0; w < 11; ++w) {
    int ai = base + w;
    a[w] = (ai >= 0 && ai < T_IN) ? ap[ai] : 0.f;
  }
  float w1[7];
  #pragma unroll
  for (int j = 0; j < 7; ++j) w1[j] = ew1[ic*7+j];
  float b1 = eb1[ic];
  #pragma unroll
  for (int jj = 0; jj < 5; ++jj) {
    int tcol = HOP * s + jj - 2;
    float v = 0.f;
    if (tcol >= 0) {
      float acc = b1;
      #pragma unroll
      for (int j = 0; j < 7; ++j) acc = fmaf(w1[j], a[jj + j], acc);
      v = fmaxf(acc, 0.f);
    }
    int k = ic * 5 + jj;
    int kt = k >> 5;
    int lane2 = ((k >> 3) & 3) * 16 + (n & 15);
    long idx = ((long)((n >> 4) * 40 + kt)) * 512 + lane2 * 8 + (k & 7);
    uint bi = __float_as_uint(v);
    X1h[idx] = (ushort)(bi >> 16);
    float r = v - __uint_as_float(bi & 0xffff0000u);
    X1l[idx] = (ushort)(__float_as_uint(r) >> 16);
  }
}

// ---------------- encoder conv2 as GEMM: h2c[n][oc] = relu(eb2 + ew2 . X1^T) ------
// Fragment-packed operands, 4-wave blocks, disjoint 10 kt per wave, barrier-free
// K-loop, LDS reduce epilogue.
__global__ __launch_bounds__(256) void gemm_enc2(const ushort* __restrict__ aH,
    const ushort* __restrict__ aL, const ushort* __restrict__ bH,
    const ushort* __restrict__ bL, const float* __restrict__ eb2,
    float* __restrict__ h2c) {
  __shared__ __align__(16) float red[4 * 2048];   // 32 KB
  const int tid = threadIdx.x;
  const int w = tid >> 6, lane = tid & 63;
  const int l15 = lane & 15, quad = lane >> 4;
  const int m0 = blockIdx.x * 32, n0 = blockIdx.y * 64;
  const int mt0 = blockIdx.x * 2, nt0 = blockIdx.y * 4;
  const int kt0 = w * 10;
  f32x4 acc[2][4] = {};
  const ushort* aHB = aH + ((long)(mt0 * 40 + kt0)) * 512 + lane * 8;
  const ushort* aLB = aL + ((long)(mt0 * 40 + kt0)) * 512 + lane * 8;
  const ushort* bHB = bH + ((long)(nt0 * 40 + kt0)) * 512 + lane * 8;
  const ushort* bLB = bL + ((long)(nt0 * 40 + kt0)) * 512 + lane * 8;
  for (int kt = 0; kt < 10; ++kt) {
    short8 ah[2], al[2], bh[4], bl[4];
    #pragma unroll
    for (int i = 0; i < 2; ++i) {
      long o = ((long)(i * 40 + kt)) * 512;
      ah[i] = *(const short8*)(aHB + o);
      al[i] = *(const short8*)(aLB + o);
    }
    #pragma unroll
    for (int f = 0; f < 4; ++f) {
      long o = ((long)(f * 40 + kt)) * 512;
      bh[f] = *(const short8*)(bHB + o);
      bl[f] = *(const short8*)(bLB + o);
    }
    #pragma unroll
    for (int i = 0; i < 2; ++i)
      #pragma unroll
      for (int j = 0; j < 4; ++j) {
        acc[i][j] = __builtin_amdgcn_mfma_f32_16x16x32_bf16(ah[i], bh[j], acc[i][j], 0, 0, 0);
        acc[i][j] = __builtin_amdgcn_mfma_f32_16x16x32_bf16(ah[i], bl[j], acc[i][j], 0, 0, 0);
        acc[i][j] = __builtin_amdgcn_mfma_f32_16x16x32_bf16(al[i], bh[j], acc[i][j], 0, 0, 0);
      }
  }
  #pragma unroll
  for (int i = 0; i < 2; ++i)
    #pragma unroll
    for (int j = 0; j < 4; ++j)
      *(float4*)&red[w * 2048 + (i * 4 + j) * 256 + lane * 4] = *(float4*)&acc[i][j];
  __syncthreads();
  #pragma unroll
  for (int q = 0; q < 2; ++q) {
    const int c = 2 * w + q;
    const int i = c >> 2, j = c & 3;
    float4 s = make_float4(0.f, 0.f, 0.f, 0.f);
    #pragma unroll
    for (int g = 0; g < 4; ++g) {
      float4 t4 = *(const float4*)&red[g * 2048 + c * 256 + lane * 4];
      s.x += t4.x; s.y += t4.y; s.z += t4.z; s.w += t4.w;
    }
    const int obase = m0 + i * 16 + quad * 4;
    float4 bias = *(const float4*)(eb2 + obase);
    const int n = n0 + j * 16 + l15;
    float4 out;
    out.x = fmaxf(s.x + bias.x, 0.f);
    out.y = fmaxf(s.y + bias.y, 0.f);
    out.z = fmaxf(s.z + bias.z, 0.f);
    out.w = fmaxf(s.w + bias.w, 0.f);
    *(float4*)(h2c + (long)n * C2 + obase) = out;
  }
}

// ---------------- im2col for conv3 (k3,p1), fragment-packed bf16 hi/lo ----------
__global__ void k_h2x(const float* __restrict__ h2c, ushort* __restrict__ h2xph,
                      ushort* __restrict__ h2xpl) {
  int idx = blockIdx.x * 256 + threadIdx.x;
  const int total = NN * 1536;
  for (; idx < total; idx += gridDim.x * 256) {
    int grp = idx >> 9;
    int r = idx & 511;
    int e = r & 7, lane = r >> 3;
    int quad = lane >> 4, l15 = lane & 15;
    int nt = grp / 48, kt = grp - nt * 48;
    int n = nt * 16 + l15;
    int k = kt * 32 + quad * 8 + e;
    int ic = k / 3, j = k - ic * 3;
    int s2 = (n & 127) + j - 1;
    int b = n >> 7;
    float v = (s2 >= 0 && s2 < SS) ? h2c[(long)(b*SS + s2)*C2 + ic] : 0.f;
    uint bi = __float_as_uint(v);
    h2xph[idx] = (ushort)(bi >> 16);
    float rr = v - __uint_as_float(bi & 0xffff0000u);
    h2xpl[idx] = (ushort)(__float_as_uint(rr) >> 16);
  }
}

// ---------------- S1: h3 = ew3 . h2x^T + eb3 (fragment-packed everything) -------
__global__ __launch_bounds__(256) void gemm_h3(const ushort* __restrict__ aH,
    const ushort* __restrict__ aL, const ushort* __restrict__ bH,
    const ushort* __restrict__ bL, const float* __restrict__ eb3,
    ushort* __restrict__ h3ph, ushort* __restrict__ h3pl) {
  __shared__ __align__(16) float red[4 * 4096];   // 64 KB
  const int tid = threadIdx.x;
  const int w = tid >> 6, lane = tid & 63;
  const int l15 = lane & 15, quad = lane >> 4;
  // XCD-aware swizzle: 448 blocks = 8 xcd x 14 m-chunks x 4 n-chunks
  const int bid = blockIdx.x;
  const int xcd = bid & 7, q = bid >> 3;
  const int mchunk = xcd * 14 + (q >> 2);
  const int nchunk = q & 3;
  const int mtL0 = mchunk * 4, nt0 = nchunk * 4, n0 = nchunk * 64;
  const int kt0 = w * 12;
  f32x4 acc[4][4] = {};
  const ushort* aHB = aH + ((long)(mtL0 * 48 + kt0)) * 512 + lane * 8;
  const ushort* aLB = aL + ((long)(mtL0 * 48 + kt0)) * 512 + lane * 8;
  const ushort* bHB = bH + ((long)(nt0 * 48 + kt0)) * 512 + lane * 8;
  const ushort* bLB = bL + ((long)(nt0 * 48 + kt0)) * 512 + lane * 8;
  for (int kt = 0; kt < 12; ++kt) {
    short8 ah[4], al[4], bh[4], bl[4];
    #pragma unroll
    for (int f = 0; f < 4; ++f) {
      long o = ((long)(f * 48 + kt)) * 512;
      ah[f] = *(const short8*)(aHB + o);
      al[f] = *(const short8*)(aLB + o);
      bh[f] = *(const short8*)(bHB + o);
      bl[f] = *(const short8*)(bLB + o);
    }
    #pragma unroll
    for (int i = 0; i < 4; ++i)
      #pragma unroll
      for (int j = 0; j < 4; ++j) {
        acc[i][j] = __builtin_amdgcn_mfma_f32_16x16x32_bf16(ah[i], bh[j], acc[i][j], 0, 0, 0);
        acc[i][j] = __builtin_amdgcn_mfma_f32_16x16x32_bf16(ah[i], bl[j], acc[i][j], 0, 0, 0);
        acc[i][j] = __builtin_amdgcn_mfma_f32_16x16x32_bf16(al[i], bh[j], acc[i][j], 0, 0, 0);
      }
  }
  #pragma unroll
  for (int i = 0; i < 4; ++i)
    #pragma unroll
    for (int j = 0; j < 4; ++j)
      *(float4*)&red[w * 4096 + (i * 4 + j) * 256 + lane * 4] = *(float4*)&acc[i][j];
  __syncthreads();
  const int mg0 = mchunk * 64 + w * 16 + quad * 4;
  float4 bias = *(const float4*)(eb3 + mg0);
  const int ktS = mg0 >> 5, quadk = (mg0 >> 3) & 3, es = mg0 & 7;
  #pragma unroll
  for (int j = 0; j < 4; ++j) {
    float4 s = *(const float4*)&red[(w * 4 + j) * 256 + lane * 4];
    #pragma unroll
    for (int r = 1; r < 4; ++r) {
      float4 tt = *(const float4*)&red[r * 4096 + (w * 4 + j) * 256 + lane * 4];
      s.x += tt.x; s.y += tt.y; s.z += tt.z; s.w += tt.w;
    }
    const int n = n0 + j * 16 + l15;
    float v0 = s.x + bias.x;
    float v1 = s.y + bias.y;
    float v2 = s.z + bias.z;
    float v3 = s.w + bias.w;
    uint b0 = __float_as_uint(v0), b1 = __float_as_uint(v1);
    uint b2 = __float_as_uint(v2), b3 = __float_as_uint(v3);
    uint2 hp;
    hp.x = (b0 >> 16) | (b1 & 0xffff0000u);
    hp.y = (b2 >> 16) | (b3 & 0xffff0000u);
    float r0 = v0 - __uint_as_float(b0 & 0xffff0000u);
    float r1 = v1 - __uint_as_float(b1 & 0xffff0000u);
    float r2 = v2 - __uint_as_float(b2 & 0xffff0000u);
    float r3 = v3 - __uint_as_float(b3 & 0xffff0000u);
    uint2 lp;
    lp.x = (__float_as_uint(r0) >> 16) | (__float_as_uint(r1) & 0xffff0000u);
    lp.y = (__float_as_uint(r2) >> 16) | (__float_as_uint(r3) & 0xffff0000u);
    long off = ((long)((n >> 4) * 224 + ktS)) * 512 + (quadk * 16 + (n & 15)) * 8 + es;
    *(uint2*)(h3ph + off) = hp;
    *(uint2*)(h3pl + off) = lp;
  }
}

// ---------------- S2: scores + FUSED partial argmin ----------
__global__ __launch_bounds__(256) void gemm_scores(const ushort* __restrict__ aH,
    const ushort* __restrict__ aL, const ushort* __restrict__ bH,
    const ushort* __restrict__ bL, const float* __restrict__ cbn,
    float* __restrict__ pval, int* __restrict__ pidx) {
  __shared__ __align__(16) float red[4 * 4096];   // 64 KB
  __shared__ float wv_[4 * 64];
  __shared__ int   wi_[4 * 64];
  const int tid = threadIdx.x;
  const int w = tid >> 6, lane = tid & 63;
  const int l15 = lane & 15, quad = lane >> 4;
  const int m0 = blockIdx.x * 64, n0 = blockIdx.y * 64, z = blockIdx.z;
  const int mt0 = blockIdx.x * 4;
  const int kt0 = w * 4;
  f32x4 acc[4][4] = {};
  const ushort* aHB = aH + ((long)((z * 64 + mt0) * 16 + kt0)) * 512 + lane * 8;
  const ushort* aLB = aL + ((long)((z * 64 + mt0) * 16 + kt0)) * 512 + lane * 8;
  const ushort* bHB = bH + ((long)((n0 >> 4) * 224 + z * 16 + kt0)) * 512 + lane * 8;
  const ushort* bLB = bL + ((long)((n0 >> 4) * 224 + z * 16 + kt0)) * 512 + lane * 8;
  for (int kt = 0; kt < 4; ++kt) {
    short8 ah[4], al[4], bh[4], bl[4];
    #pragma unroll
    for (int f = 0; f < 4; ++f) {
      long oa = ((long)(f * 16 + kt)) * 512;
      long ob = ((long)(f * 224 + kt)) * 512;
      ah[f] = *(const short8*)(aHB + oa);
      al[f] = *(const short8*)(aLB + oa);
      bh[f] = *(const short8*)(bHB + ob);
      bl[f] = *(const short8*)(bLB + ob);
    }
    #pragma unroll
    for (int i = 0; i < 4; ++i)
      #pragma unroll
      for (int j = 0; j < 4; ++j) {
        acc[i][j] = __builtin_amdgcn_mfma_f32_16x16x32_bf16(ah[i], bh[j], acc[i][j], 0, 0, 0);
        acc[i][j] = __builtin_amdgcn_mfma_f32_16x16x32_bf16(ah[i], bl[j], acc[i][j], 0, 0, 0);
        acc[i][j] = __builtin_amdgcn_mfma_f32_16x16x32_bf16(al[i], bh[j], acc[i][j], 0, 0, 0);
      }
  }
  #pragma unroll
  for (int i = 0; i < 4; ++i)
    #pragma unroll
    for (int j = 0; j < 4; ++j)
      *(float4*)&red[w * 4096 + (i * 4 + j) * 256 + lane * 4] = *(float4*)&acc[i][j];
  __syncthreads();
  const int vbase = m0 + w * 16 + quad * 4;
  float4 cn = *(const float4*)(cbn + z * VOC + vbase);
  #pragma unroll
  for (int j = 0; j < 4; ++j) {
    float4 s = *(const float4*)&red[(w * 4 + j) * 256 + lane * 4];
    #pragma unroll
    for (int r = 1; r < 4; ++r) {
      float4 tt = *(const float4*)&red[r * 4096 + (w * 4 + j) * 256 + lane * 4];
      s.x += tt.x; s.y += tt.y; s.z += tt.z; s.w += tt.w;
    }
    float o0 = cn.x - 2.f * s.x;
    float o1 = cn.y - 2.f * s.y;
    float o2 = cn.z - 2.f * s.z;
    float o3 = cn.w - 2.f * s.w;
    float bv = o0; int bm = vbase;
    if (o1 < bv) { bv = o1; bm = vbase + 1; }
    if (o2 < bv) { bv = o2; bm = vbase + 2; }
    if (o3 < bv) { bv = o3; bm = vbase + 3; }
    #pragma unroll
    for (int off = 16; off <= 32; off <<= 1) {
      float ov = __shfl_xor(bv, off);
      int om = __shfl_xor(bm, off);
      if (ov < bv || (ov == bv && om < bm)) { bv = ov; bm = om; }
    }
    if (quad == 0) { wv_[w * 64 + j * 16 + l15] = bv; wi_[w * 64 + j * 16 + l15] = bm; }
  }
  __syncthreads();
  if (tid < 64) {
    float bv = wv_[tid]; int bm = wi_[tid];
    #pragma unroll
    for (int g = 1; g < 4; ++g) {
      float ov = wv_[g * 64 + tid]; int om = wi_[g * 64 + tid];
      if (ov < bv || (ov == bv && om < bm)) { bv = ov; bm = om; }
    }
    long prow = (long)z * NN + n0 + tid;
    pval[prow * 16 + blockIdx.x] = bv;
    pidx[prow * 16 + blockIdx.x] = bm;
  }
}

// ---------------- final argmin over the 16 m-chunk partials ----------------
__global__ void k_argmin2(const float* __restrict__ pval, const int* __restrict__ pidx,
                          int* __restrict__ codes) {
  int row = blockIdx.x * 256 + threadIdx.x;   // z*256+n, 3584 total
  if (row >= NCBK * NN) return;
  const float* pv = pval + (long)row * 16;
  const int*   pi = pidx + (long)row * 16;
  float bv = pv[0]; int bm = pi[0];
  #pragma unroll
  for (int c = 1; c < 16; ++c) {
    float v = pv[c]; int m = pi[c];
    if (v < bv || (v == bv && m < bm)) { bv = v; bm = m; }
  }
  codes[row] = bm;
}

// ---------------- gather q as bf16 fragments ----------------
__global__ void k_gather_qbf(const float* __restrict__ cb, const int* __restrict__ codes,
                             ushort* __restrict__ qp) {
  int o = blockIdx.x * 256 + threadIdx.x;
  const int total = NN * C3 / 8;                 // 229376
  if (o >= total) return;
  int frag = o >> 6, r = o & 63;
  int quad = r >> 4, l15 = r & 15;
  int nt = frag / 224, kt = frag - nt * 224;
  int n = nt * 16 + l15;
  int kglob = kt * 32 + quad * 8;
  int kcb = kglob >> 9, d0 = kglob & 511;
  int code = codes[kcb * NN + n];
  const float* s = cb + ((long)(kcb * VOC + code)) * DIMV + d0;
  float4 x0 = *(const float4*)s;
  float4 x1 = *(const float4*)(s + 4);
  uint4 u;
  u.x = (uint)f2bf(x0.x) | ((uint)f2bf(x0.y) << 16);
  u.y = (uint)f2bf(x0.z) | ((uint)f2bf(x0.w) << 16);
  u.z = (uint)f2bf(x1.x) | ((uint)f2bf(x1.y) << 16);
  u.w = (uint)f2bf(x1.z) | ((uint)f2bf(x1.w) << 16);
  ((uint4*)qp)[o] = u;
}

// ---------------- decoder convT GEMM via MFMA bf16 (fragment-packed) ----------------
// 16-wave blocks, disjoint K-1/16 per wave (14 kt), staged 4-round LDS reduce.
__global__ __launch_bounds__(1024) void gemm_a1_mfma(const ushort* __restrict__ dw1p,
    const ushort* __restrict__ qp, float* __restrict__ a1raw) {
  __shared__ __align__(16) float red[4 * 4096];
  const int tid = threadIdx.x;
  const int w = tid >> 6, lane = tid & 63;
  const int l15 = lane & 15, quad = lane >> 4;
  const int mt0 = blockIdx.x * 4, nt0 = blockIdx.y * 4;
  const int kt0 = w * 14;
  f32x4 acc[4][4] = {};
  const ushort* aB = dw1p + ((long)(mt0 * 224 + kt0)) * 512 + lane * 8;
  const ushort* bB = qp   + ((long)(nt0 * 224 + kt0)) * 512 + lane * 8;
  #pragma unroll 2
  for (int kt = 0; kt < 14; ++kt) {
    short8 ah[4], bh[4];
    #pragma unroll
    for (int f = 0; f < 4; ++f) {
      ah[f] = *(const short8*)(aB + ((long)(f * 224 + kt)) * 512);
      bh[f] = *(const short8*)(bB + ((long)(f * 224 + kt)) * 512);
    }
    #pragma unroll
    for (int i = 0; i < 4; ++i)
      #pragma unroll
      for (int j = 0; j < 4; ++j)
        acc[i][j] = __builtin_amdgcn_mfma_f32_16x16x32_bf16(ah[i], bh[j], acc[i][j], 0, 0, 0);
  }
  float4 rsum = make_float4(0.f, 0.f, 0.f, 0.f);
  #pragma unroll
  for (int r = 0; r < 4; ++r) {
    if ((w >> 2) == r) {
      #pragma unroll
      for (int i = 0; i < 4; ++i)
        #pragma unroll
        for (int j = 0; j < 4; ++j)
          *(float4*)&red[(w & 3) * 4096 + (i * 4 + j) * 256 + lane * 4] = *(float4*)&acc[i][j];
    }
    __syncthreads();
    #pragma unroll
    for (int g = 0; g < 4; ++g) {
      float4 t4 = *(const float4*)&red[g * 4096 + w * 256 + lane * 4];
      rsum.x += t4.x; rsum.y += t4.y; rsum.z += t4.z; rsum.w += t4.w;
    }
    __syncthreads();
  }
  const int ci = w >> 2, cj = w & 3;
  const int n = nt0 * 16 + cj * 16 + l15;
  const int mb = mt0 * 16 + ci * 16 + quad * 4;
  float v[4] = {rsum.x, rsum.y, rsum.z, rsum.w};
  #pragma unroll
  for (int reg = 0; reg < 4; ++reg) {
    int m = mb + reg;
    int c = m / 5, jj = m - c * 5;
    a1raw[((long)(n * 5 + jj)) * C2 + c] = v[reg];
  }
}

// ---------------- k_x2: build conv2 im2col X fragment-packed (bf16 hi/lo) -------
__global__ void k_x2(const float* __restrict__ a1raw, const float* __restrict__ ab1g,
                     const float* __restrict__ db1, ushort* __restrict__ Xh,
                     ushort* __restrict__ Xl) {
  int idx = blockIdx.x * 256 + threadIdx.x;
  const int total = 2304 * 2560;
  for (; idx < total; idx += gridDim.x * 256) {
    int grp = idx >> 9;
    int r = idx & 511;
    int e = r & 7, lane = r >> 3;
    int quad = lane >> 4, l15 = lane & 15;
    int nt = grp / 80, kt = grp - nt * 80;
    int nu = nt * 16 + l15;
    int ck = kt * 32 + quad * 8 + e;
    int n = nu / 9, u = nu - n * 9;
    int c = ck / 5, jj = ck - c * 5;
    int w = u + jj;
    int s = n & 127;
    int tc = HOP * s - 6 + w;
    float v;
    if (tc < 0 || tc > TOUT - 1) v = 0.f;
    else if (w >= 4 && w <= 8)
      v = fmaxf(db1[c] + a1raw[((long)(n * 5 + (w - 4))) * C2 + c], 0.f);
    else v = ab1g[c];
    uint bi = __float_as_uint(v);
    Xh[idx] = (ushort)(bi >> 16);
    float rr = v - __uint_as_float(bi & 0xffff0000u);
    Xl[idx] = (ushort)(__float_as_uint(rr) >> 16);
  }
}

// ---------------- decoder conv2 as GEMM: a2act = relu(db2 + dw2 . X^T) ----------
// Fragment-packed operands. 16-wave blocks (was 4-wave, 0.56 waves/SIMD),
// disjoint 5 kt per wave, staged 4-round LDS reduce (gemm_a1 structure).
__global__ __launch_bounds__(1024) void gemm_dec2(const ushort* __restrict__ aH,
    const ushort* __restrict__ aL, const ushort* __restrict__ bH,
    const ushort* __restrict__ bL, const float* __restrict__ db2,
    float* __restrict__ a2act) {
  __shared__ __align__(16) float red[4 * 4096];   // 64 KB
  const int tid = threadIdx.x;
  const int w = tid >> 6, lane = tid & 63;        // w in 0..15
  const int l15 = lane & 15, quad = lane >> 4;
  const int mt0 = blockIdx.x * 4, nt0 = blockIdx.y * 4;
  const int kt0 = w * 5;                          // disjoint 5 k-tiles per wave
  f32x4 acc[4][4] = {};
  const ushort* aHB = aH + ((long)(mt0 * 80 + kt0)) * 512 + lane * 8;
  const ushort* aLB = aL + ((long)(mt0 * 80 + kt0)) * 512 + lane * 8;
  const ushort* bHB = bH + ((long)(nt0 * 80 + kt0)) * 512 + lane * 8;
  const ushort* bLB = bL + ((long)(nt0 * 80 + kt0)) * 512 + lane * 8;
  for (int kt = 0; kt < 5; ++kt) {
    short8 ah[4], al[4], bh[4], bl[4];
    #pragma unroll
    for (int f = 0; f < 4; ++f) {
      long o = ((long)(f * 80 + kt)) * 512;
      ah[f] = *(const short8*)(aHB + o);
      al[f] = *(const short8*)(aLB + o);
      bh[f] = *(const short8*)(bHB + o);
      bl[f] = *(const short8*)(bLB + o);
    }
    #pragma unroll
    for (int i = 0; i < 4; ++i)
      #pragma unroll
      for (int j = 0; j < 4; ++j) {
        acc[i][j] = __builtin_amdgcn_mfma_f32_16x16x32_bf16(ah[i], bh[j], acc[i][j], 0, 0, 0);
        acc[i][j] = __builtin_amdgcn_mfma_f32_16x16x32_bf16(ah[i], bl[j], acc[i][j], 0, 0, 0);
        acc[i][j] = __builtin_amdgcn_mfma_f32_16x16x32_bf16(al[i], bh[j], acc[i][j], 0, 0, 0);
      }
  }
  // staged 4-round cross-wave reduce (chunk c = i*4+j; wave w owns chunk w)
  float4 rsum = make_float4(0.f, 0.f, 0.f, 0.f);
  #pragma unroll
  for (int r = 0; r < 4; ++r) {
    if ((w >> 2) == r) {
      #pragma unroll
      for (int i = 0; i < 4; ++i)
        #pragma unroll
        for (int j = 0; j < 4; ++j)
          *(float4*)&red[(w & 3) * 4096 + (i * 4 + j) * 256 + lane * 4] = *(float4*)&acc[i][j];
    }
    __syncthreads();
    #pragma unroll
    for (int g = 0; g < 4; ++g) {
      float4 t4 = *(const float4*)&red[g * 4096 + w * 256 + lane * 4];
      rsum.x += t4.x; rsum.y += t4.y; rsum.z += t4.z; rsum.w += t4.w;
    }
    __syncthreads();
  }
  const int ci = w >> 2, cj = w & 3;
  const int n = nt0 * 16 + cj * 16 + l15;
  const int mb = mt0 * 16 + ci * 16 + quad * 4;
  float4 bias = *(const float4*)(db2 + mb);
  float4 out;
  out.x = fmaxf(rsum.x + bias.x, 0.f);
  out.y = fmaxf(rsum.y + bias.y, 0.f);
  out.z = fmaxf(rsum.z + bias.z, 0.f);
  out.w = fmaxf(rsum.w + bias.w, 0.f);
  *(float4*)(a2act + (long)n * C1 + mb) = out;
}

// ---------------- decoder conv3+tanh + constant fill (merged) ----------------
// Block (b,s) owns output cols [768s-384, 768s+384) (clipped): computes the
// <=15 active cols via conv, fills the rest with the constant tanh value.
__global__ __launch_bounds__(256) void k_dec3(const float* __restrict__ a2act,
    const float* __restrict__ ab2g, const float* __restrict__ dw3,
    const float* __restrict__ db3, const float* __restrict__ cconst,
    float* __restrict__ outp) {
  __shared__ float sa2[9 * C1];
  __shared__ float sb[C1];
  int n = blockIdx.x;
  int s = n & 127, b = n >> 7;
  int t = threadIdx.x;
  for (int i = t; i < 9 * C1; i += 256) sa2[i] = a2act[(long)n * 9 * C1 + i];
  sb[t] = ab2g[t];
  __syncthreads();
  // fill owned non-active cols with the constant
  float vfill = cconst[0];
  int lo = (s == 0) ? 0 : HOP * s - 384;
  int hi = (s == SS - 1) ? TOUT : HOP * s + 384;
  for (int tc = lo + t; tc < hi; tc += 256) {
    int d = tc - HOP * s;
    if (d < -7 || d > 7) outp[(long)b * TOUT + tc] = vfill;
  }
  int wv = t >> 6, lane = t & 63;
  float b3 = db3[0];
  for (int w15 = wv; w15 < 15; w15 += 4) {
    int tc = HOP * s - 7 + w15;
    if (tc < 0 || tc > TOUT - 1) continue;
    float part = 0.f;
    for (int cc = lane; cc < C1; cc += 64) {
      #pragma unroll
      for (int j = 0; j < 7; ++j) {
        int wcol = tc + j - 3;
        float x;
        if (wcol < 0 || wcol > TOUT - 1) x = 0.f;
        else {
          int du = wcol - (HOP * s - 4);
          x = (du >= 0 && du <= 8) ? sa2[du * C1 + cc] : sb[cc];
        }
        part = fmaf(dw3[cc*7+j], x, part);
      }
    }
    for (int off = 32; off; off >>= 1) part += __shfl_down(part, off);
    if (lane == 0) outp[(long)b * TOUT + tc] = tanhf(part + b3);
  }
}

extern "C" void kernel_launch(void* const* d_in, const int* in_sizes, int n_in,
                              void* d_out, int out_size, void* d_ws, size_t ws_size,
                              hipStream_t stream) {
  const float* audio = (const float*)d_in[0];
  const float* cb    = (const float*)d_in[1];
  const float* ew1   = (const float*)d_in[2];
  const float* eb1   = (const float*)d_in[3];
  const float* ew2   = (const float*)d_in[4];
  const float* eb2   = (const float*)d_in[5];
  const float* ew3   = (const float*)d_in[6];
  const float* eb3   = (const float*)d_in[7];
  const float* dw1   = (const float*)d_in[8];
  const float* db1   = (const float*)d_in[9];
  const float* dw2   = (const float*)d_in[10];
  const float* db2   = (const float*)d_in[11];
  const float* dw3   = (const float*)d_in[12];
  const float* db3   = (const float*)d_in[13];
  float* outp = (float*)d_out;
  float* ws = (float*)d_ws;

  float*  cbn    = ws + OFF_CBN;
  float*  ab1    = ws + OFF_AB1;
  float*  ab2    = ws + OFF_AB2;
  float*  cconst = ws + OFF_CCONST;
  float*  h2c    = ws + OFF_H2C;
  ushort* h2xph  = (ushort*)(ws + OFF_H2XH);
  ushort* h2xpl  = (ushort*)(ws + OFF_H2XL);
  ushort* h3ph   = (ushort*)(ws + OFF_H3H);
  ushort* h3pl   = (ushort*)(ws + OFF_H3L);
  ushort* X1h    = (ushort*)(ws + OFF_X1H);
  ushort* X1l    = (ushort*)(ws + OFF_X1L);
  ushort* cbph   = (ushort*)(ws + OFF_CBPH);
  ushort* cbpl   = (ushort*)(ws + OFF_CBPL);
  ushort* ew3ph  = (ushort*)(ws + OFF_EW3PH);
  ushort* ew3pl  = (ushort*)(ws + OFF_EW3PL);
  ushort* ew2ph  = (ushort*)(ws + OFF_EW2PH);
  ushort* ew2pl  = (ushort*)(ws + OFF_EW2PL);
  float*  pval   = ws + OFF_PVAL;
  int*    pidx   = (int*)(ws + OFF_PIDX);
  ushort* dw1p   = (ushort*)(ws + OFF_DW1P);
  ushort* dw2ph  = (ushort*)(ws + OFF_DW2PH);
  ushort* dw2pl  = (ushort*)(ws + OFF_DW2PL);
  ushort* Xh     = (ushort*)(ws + OFF_XH);
  ushort* Xl     = (ushort*)(ws + OFF_XL);
  int*    codes  = (int*)(ws + OFF_CODES);
  ushort* qp     = (ushort*)(ws + OFF_QBF);
  float*  a1raw  = ws + OFF_A1RAW;
  float*  a2act  = ws + OFF_A2ACT;

  // all weight packs in one BW-saturating launch (was 5 kernels)
  k_packw<<<11392, 256, 0, stream>>>(cb, ew2, ew3, dw2, dw1,
      cbph, cbpl, cbn, ew2ph, ew2pl, ew3ph, ew3pl, dw2ph, dw2pl, dw1p);
  k_prep_ab2<<<C1, 256, 0, stream>>>(db1, dw2, db2, ab1, ab2);
  k_prep_c<<<1, 256, 0, stream>>>(dw3, db3, ab2, cconst);
  k_enc1<<<NN, 256, 0, stream>>>(audio, ew1, eb1, X1h, X1l);
  gemm_enc2<<<dim3(16, 4), 256, 0, stream>>>(ew2ph, ew2pl, X1h, X1l, eb2, h2c);
  k_h2x<<<384, 256, 0, stream>>>(h2c, h2xph, h2xpl);
  gemm_h3<<<448, 256, 0, stream>>>(ew3ph, ew3pl, h2xph, h2xpl, eb3, h3ph, h3pl);
  gemm_scores<<<dim3(16, 4, 14), 256, 0, stream>>>(cbph, cbpl, h3ph, h3pl, cbn, pval, pidx);
  k_argmin2<<<14, 256, 0, stream>>>(pval, pidx, codes);
  k_gather_qbf<<<896, 256, 0, stream>>>(cb, codes, qp);
  gemm_a1_mfma<<<dim3(40, 4), 1024, 0, stream>>>(dw1p, qp, a1raw);
  // Xh/Xl overlap h3p/X1 (dead after gemm_scores) — stream-ordered after gemm_a1
  k_x2<<<4096, 256, 0, stream>>>(a1raw, ab1, db1, Xh, Xl);
  gemm_dec2<<<dim3(4, 36), 1024, 0, stream>>>(dw2ph, dw2pl, Xh, Xl, db2, a2act);
  k_dec3<<<NN, 256, 0, stream>>>(a2act, ab2, dw3, db3, cconst, outp);
}

// Round 12
// 377.702 us; speedup vs baseline: 1.0352x; 1.0352x over previous
//
#include <hip/hip_runtime.h>
#include <hip/hip_bf16.h>
#include <math.h>

#define T_IN 98304
#define SS 128
#define NBATCH 2
#define NN 256          // NBATCH*SS
#define C1 256
#define C2 512
#define C3 7168
#define NCBK 14
#define DIMV 512
#define VOC 1024
#define TOUT 97537
#define HOP 768

// ws layout (float offsets). Harness allocates ~280 MB ws; fresh space beyond
// 11880720 confirmed usable (rounds 7-11). This layout uses ~163 MB.
#define OFF_CBN    0L          // 14336
#define OFF_AB1    14336L      // 512
#define OFF_AB2    14848L      // 256
#define OFF_CCONST 15104L      // 16
#define OFF_H2C    15120L      // 131072   (n*512+ic), n=b*128+s
// h2xp: fragment-packed bf16 [16 nt][48 kt][512] per plane (196608 fl each)
#define OFF_H2XH   146192L     // ends 342800
#define OFF_H2XL   342800L     // ends 539408
// h3p: fragment-packed bf16 (B-operand layout for gemm_scores)
#define OFF_H3H    539408L     // ends 1456912
#define OFF_H3L    1456912L    // ends 2374416
// X1p fragment-packed bf16 [16 nt][40 kt][512] (163840 fl each)
#define OFF_X1H    2374416L    // ends 2538256
#define OFF_X1L    2538256L    // ends 2702096
// Xp hi/lo fragment-packed [144 nt][80 kt][512] per plane (2949120 fl each)
// OVERLAP h3p/X1 (dead after gemm_scores; k_x2 launches after gemm_a1).
#define OFF_XH     539408L     // ends 3488528
#define OFF_XL     3488528L    // ends 6437648
#define OFF_CODES  9714448L    // 3584 ints
#define OFF_QBF    9718032L    // 917504 fl (bf16 fragment-packed [16 nt][224 kt][512])
#define OFF_A1RAW  10635536L   // 655360   ((n*5+j)*512 + c)  pre-bias/relu
#define OFF_A2ACT  11290896L   // 589824   ((n*9+u)*256 + o)  post-relu
// ---- fresh space (no aliasing) ----
#define OFF_CBPH   11880720L   // ends 15550736
#define OFF_CBPL   15550736L   // ends 19220752
#define OFF_EW3PH  19220752L   // ends 24725776
#define OFF_EW3PL  24725776L   // ends 30230800
#define OFF_EW2PH  30230800L   // ends 30558480
#define OFF_EW2PL  30558480L   // ends 30886160
#define OFF_PVAL   30886160L   // ends 30943504
#define OFF_PIDX   30943504L   // ends 31000848
#define OFF_DW1P   31000848L   // ends 40175888  (bf16 [160 mt][224 kt][512])
#define OFF_DW2PH  40175888L   // ends 40503568  (bf16 [16 mt][80 kt][512])
#define OFF_DW2PL  40503568L   // ends 40831248
// total ~163.3 MB

typedef __attribute__((ext_vector_type(8))) short short8;
typedef __attribute__((ext_vector_type(4))) float f32x4;

static __device__ inline ushort f2bf(float x) {
  __hip_bfloat16 h = __float2bfloat16(x);
  return *reinterpret_cast<ushort*>(&h);
}

// exact 2-term split: x = hi + lo + O(2^-16 |x|); truncation split, residual exact
static __device__ inline void split8(const float4 x0, const float4 x1,
                                     short8& h, short8& l) {
  float xs[8] = {x0.x, x0.y, x0.z, x0.w, x1.x, x1.y, x1.z, x1.w};
  #pragma unroll
  for (int e = 0; e < 8; ++e) {
    uint b = __float_as_uint(xs[e]);
    h[e] = (short)(b >> 16);
    float r = xs[e] - __uint_as_float(b & 0xffff0000u);
    l[e] = (short)(__float_as_uint(r) >> 16);
  }
}

// ---------------- ONE pack kernel for all weights ----------------
// Sections by blockIdx.x:
//  [0,896)      : cb -> cbp hi/lo + row norms (zmt = bid); 4 units/thread
//  [896,1216)   : ew2 -> ew2p (1 unit/thread)
//  [1216,2560)  : ew3 -> ew3p (4 independent units/thread — ILP fix; was
//                 1 unit/thread at 2.6 TB/s, latency-limited)
//  [2560,2880)  : dw2 -> dw2p (1 unit/thread)
//  [2880,7360)  : dw1 -> dw1p (LDS transpose, kb = idx/40, mb = idx%40)
__global__ __launch_bounds__(256) void k_packw(const float* __restrict__ cb,
    const float* __restrict__ ew2, const float* __restrict__ ew3,
    const float* __restrict__ dw2, const float* __restrict__ dw1,
    ushort* __restrict__ cbph, ushort* __restrict__ cbpl, float* __restrict__ cbn,
    ushort* __restrict__ ew2ph, ushort* __restrict__ ew2pl,
    ushort* __restrict__ ew3ph, ushort* __restrict__ ew3pl,
    ushort* __restrict__ dw2ph, ushort* __restrict__ dw2pl,
    ushort* __restrict__ dw1p) {
  __shared__ __align__(16) ushort T[64 * 72];
  __shared__ float red[256];
  const int bid = blockIdx.x;
  const int t = threadIdx.x;
  if (bid < 896) {
    // ---- cbp + norms ----
    int zmt = bid;
    int lane = t & 63, fg = t >> 6;
    int quad = lane >> 4, l15 = lane & 15;
    int row = zmt * 16 + l15;
    float ss = 0.f;
    #pragma unroll
    for (int h = 0; h < 4; ++h) {
      int kt = fg * 4 + h;
      int k = kt * 32 + quad * 8;
      const float* s = cb + (long)row * DIMV + k;
      float4 x0 = *(const float4*)s;
      float4 x1 = *(const float4*)(s + 4);
      short8 hh, ll;
      split8(x0, x1, hh, ll);
      long off = ((long)zmt * 16 + kt) * 512 + lane * 8;
      *(short8*)(cbph + off) = hh;
      *(short8*)(cbpl + off) = ll;
      ss += x0.x*x0.x + x0.y*x0.y + x0.z*x0.z + x0.w*x0.w
          + x1.x*x1.x + x1.y*x1.y + x1.z*x1.z + x1.w*x1.w;
    }
    red[t] = ss;
    __syncthreads();
    if (t < 16) {
      float s = 0.f;
      #pragma unroll
      for (int g = 0; g < 16; ++g) s += red[t + g * 16];
      cbn[zmt * 16 + t] = s;
    }
  } else if (bid < 1216) {
    // ---- ew2p ----
    int o8 = (bid - 896) * 256 + t;            // < 81920
    int frag = o8 >> 6, lane = o8 & 63;
    int quad = lane >> 4, l15 = lane & 15;
    int mt = frag / 40, kt = frag - mt * 40;
    const float* s = ew2 + (long)(mt * 16 + l15) * 1280 + kt * 32 + quad * 8;
    float4 x0 = *(const float4*)s;
    float4 x1 = *(const float4*)(s + 4);
    short8 h, l;
    split8(x0, x1, h, l);
    long off = (long)o8 * 8;
    *(short8*)(ew2ph + off) = h;
    *(short8*)(ew2pl + off) = l;
  } else if (bid < 2560) {
    // ---- ew3p: 4 independent units per thread ----
    int u0 = (bid - 1216) * 1024 + t;          // 1344 blocks x 1024 units
    #pragma unroll
    for (int i = 0; i < 4; ++i) {
      int o8 = u0 + i * 256;                   // < 1376256
      int frag = o8 >> 6, lane = o8 & 63;
      int quad = lane >> 4, l15 = lane & 15;
      int mtL = frag / 48, kt = frag - mtL * 48;
      const float* s = ew3 + (long)(mtL * 16 + l15) * 1536 + kt * 32 + quad * 8;
      float4 x0 = *(const float4*)s;
      float4 x1 = *(const float4*)(s + 4);
      short8 h, l;
      split8(x0, x1, h, l);
      long off = (long)o8 * 8;
      *(short8*)(ew3ph + off) = h;
      *(short8*)(ew3pl + off) = l;
    }
  } else if (bid < 2880) {
    // ---- dw2p ----
    int o8 = (bid - 2560) * 256 + t;           // < 81920
    int frag = o8 >> 6, lane = o8 & 63;
    int quad = lane >> 4, l15 = lane & 15;
    int mt = frag / 80, kt = frag - mt * 80;
    const float* s = dw2 + (long)(mt * 16 + l15) * 2560 + kt * 32 + quad * 8;
    float4 x0 = *(const float4*)s;
    float4 x1 = *(const float4*)(s + 4);
    short8 h, l;
    split8(x0, x1, h, l);
    long off = (long)o8 * 8;
    *(short8*)(dw2ph + off) = h;
    *(short8*)(dw2pl + off) = l;
  } else {
    // ---- dw1t: [7168][2560] fp32 -> fragment-packed bf16 ----
    int idx = bid - 2880;                      // < 4480
    int kb = idx / 40, mb = idx - kb * 40;
    int k0 = kb * 64, m0 = mb * 64;
    int kk = t >> 2, mj = (t & 3) * 16;
    const float* src = dw1 + (long)(k0 + kk) * 2560 + m0 + mj;
    float x[16];
    *(float4*)&x[0]  = *(const float4*)(src);
    *(float4*)&x[4]  = *(const float4*)(src + 4);
    *(float4*)&x[8]  = *(const float4*)(src + 8);
    *(float4*)&x[12] = *(const float4*)(src + 12);
    #pragma unroll
    for (int l = 0; l < 16; ++l)
      T[(mj + l) * 72 + kk] = f2bf(x[l]);
    __syncthreads();
    int mo = t >> 2, kc = (t & 3) * 16;
    const int m = m0 + mo;
    const int mt = m >> 4, l15 = m & 15;
    #pragma unroll
    for (int h = 0; h < 2; ++h) {
      const int kk0 = kc + h * 8;
      const int kglob = k0 + kk0;
      const int kt = kglob >> 5;
      const int quad = (kglob >> 3) & 3;
      uint4 u = *(const uint4*)&T[mo * 72 + kk0];
      *(uint4*)(dw1p + ((long)(mt * 224 + kt)) * 512 + (quad * 16 + l15) * 8) = u;
    }
  }
}

// ---------------- prep A: ab1 = relu(db1); ab2[o] = relu(db2[o]+sum_c W(o,c)*ab1[c])
__global__ __launch_bounds__(256) void k_prep_ab2(const float* __restrict__ db1,
    const float* __restrict__ dw2, const float* __restrict__ db2,
    float* __restrict__ ab1, float* __restrict__ ab2) {
  __shared__ float red[256];
  int o = blockIdx.x, t = threadIdx.x;
  if (o == 0) { ab1[t] = fmaxf(db1[t], 0.f); ab1[t + 256] = fmaxf(db1[t + 256], 0.f); }
  const float* wp = dw2 + (long)o * C2 * 5;
  float acc = 0.f;
  #pragma unroll
  for (int h = 0; h < 2; ++h) {
    int c = t + h * 256;
    const float* p = wp + c * 5;
    float wsum = p[0] + p[1] + p[2] + p[3] + p[4];
    acc = fmaf(wsum, fmaxf(db1[c], 0.f), acc);
  }
  red[t] = acc;
  __syncthreads();
  for (int off = 128; off; off >>= 1) {
    if (t < off) red[t] += red[t + off];
    __syncthreads();
  }
  if (t == 0) ab2[o] = fmaxf(red[0] + db2[o], 0.f);
}

// ---------------- prep B: cconst = tanh(db3 + sum_o (sum_j dw3[o][j]) * ab2[o]) ----
__global__ __launch_bounds__(256) void k_prep_c(const float* __restrict__ dw3,
    const float* __restrict__ db3, const float* __restrict__ ab2,
    float* __restrict__ cconst) {
  __shared__ float red[256];
  int t = threadIdx.x;
  float wsum3 = 0.f;
  #pragma unroll
  for (int j = 0; j < 7; ++j) wsum3 += dw3[t*7+j];
  red[t] = wsum3 * ab2[t];
  __syncthreads();
  for (int off = 128; off; off >>= 1) {
    if (t < off) red[t] += red[t + off];
    __syncthreads();
  }
  if (t == 0) cconst[0] = tanhf(red[0] + db3[0]);
}

// ---------------- encoder conv1 (k7,p3) at the 5 cols conv2 needs ----------------
// Output written fragment-packed: X1p[(nt*40+kt)*512 + (quadk*16 + n&15)*8 + k&7]
__global__ __launch_bounds__(256) void k_enc1(const float* __restrict__ audio,
    const float* __restrict__ ew1, const float* __restrict__ eb1,
    ushort* __restrict__ X1h, ushort* __restrict__ X1l) {
  int n = blockIdx.x, ic = threadIdx.x;
  int b = n >> 7, s = n & 127;
  const float* ap = audio + (long)b * T_IN;
  int base = HOP * s - 5;           // audio idx for window pos 0
  float a[11];
  #pragma unroll
  for (int w = 0; w < 11; ++w) {
    int ai = base + w;
    a[w] = (ai >= 0 && ai < T_IN) ? ap[ai] : 0.f;
  }
  float w1[7];
  #pragma unroll
  for (int j = 0; j < 7; ++j) w1[j] = ew1[ic*7+j];
  float b1 = eb1[ic];
  #pragma unroll
  for (int jj = 0; jj < 5; ++jj) {
    int tcol = HOP * s + jj - 2;
    float v = 0.f;
    if (tcol >= 0) {
      float acc = b1;
      #pragma unroll
      for (int j = 0; j < 7; ++j) acc = fmaf(w1[j], a[jj + j], acc);
      v = fmaxf(acc, 0.f);
    }
    int k = ic * 5 + jj;
    int kt = k >> 5;
    int lane2 = ((k >> 3) & 3) * 16 + (n & 15);
    long idx = ((long)((n >> 4) * 40 + kt)) * 512 + lane2 * 8 + (k & 7);
    uint bi = __float_as_uint(v);
    X1h[idx] = (ushort)(bi >> 16);
    float r = v - __uint_as_float(bi & 0xffff0000u);
    X1l[idx] = (ushort)(__float_as_uint(r) >> 16);
  }
}

// ---------------- encoder conv2 as GEMM: h2c[n][oc] = relu(eb2 + ew2 . X1^T) ------
// Fragment-packed operands, 4-wave blocks, disjoint 10 kt per wave, barrier-free
// K-loop, LDS reduce epilogue.
__global__ __launch_bounds__(256) void gemm_enc2(const ushort* __restrict__ aH,
    const ushort* __restrict__ aL, const ushort* __restrict__ bH,
    const ushort* __restrict__ bL, const float* __restrict__ eb2,
    float* __restrict__ h2c) {
  __shared__ __align__(16) float red[4 * 2048];   // 32 KB
  const int tid = threadIdx.x;
  const int w = tid >> 6, lane = tid & 63;
  const int l15 = lane & 15, quad = lane >> 4;
  const int m0 = blockIdx.x * 32, n0 = blockIdx.y * 64;
  const int mt0 = blockIdx.x * 2, nt0 = blockIdx.y * 4;
  const int kt0 = w * 10;
  f32x4 acc[2][4] = {};
  const ushort* aHB = aH + ((long)(mt0 * 40 + kt0)) * 512 + lane * 8;
  const ushort* aLB = aL + ((long)(mt0 * 40 + kt0)) * 512 + lane * 8;
  const ushort* bHB = bH + ((long)(nt0 * 40 + kt0)) * 512 + lane * 8;
  const ushort* bLB = bL + ((long)(nt0 * 40 + kt0)) * 512 + lane * 8;
  for (int kt = 0; kt < 10; ++kt) {
    short8 ah[2], al[2], bh[4], bl[4];
    #pragma unroll
    for (int i = 0; i < 2; ++i) {
      long o = ((long)(i * 40 + kt)) * 512;
      ah[i] = *(const short8*)(aHB + o);
      al[i] = *(const short8*)(aLB + o);
    }
    #pragma unroll
    for (int f = 0; f < 4; ++f) {
      long o = ((long)(f * 40 + kt)) * 512;
      bh[f] = *(const short8*)(bHB + o);
      bl[f] = *(const short8*)(bLB + o);
    }
    #pragma unroll
    for (int i = 0; i < 2; ++i)
      #pragma unroll
      for (int j = 0; j < 4; ++j) {
        acc[i][j] = __builtin_amdgcn_mfma_f32_16x16x32_bf16(ah[i], bh[j], acc[i][j], 0, 0, 0);
        acc[i][j] = __builtin_amdgcn_mfma_f32_16x16x32_bf16(ah[i], bl[j], acc[i][j], 0, 0, 0);
        acc[i][j] = __builtin_amdgcn_mfma_f32_16x16x32_bf16(al[i], bh[j], acc[i][j], 0, 0, 0);
      }
  }
  #pragma unroll
  for (int i = 0; i < 2; ++i)
    #pragma unroll
    for (int j = 0; j < 4; ++j)
      *(float4*)&red[w * 2048 + (i * 4 + j) * 256 + lane * 4] = *(float4*)&acc[i][j];
  __syncthreads();
  #pragma unroll
  for (int q = 0; q < 2; ++q) {
    const int c = 2 * w + q;
    const int i = c >> 2, j = c & 3;
    float4 s = make_float4(0.f, 0.f, 0.f, 0.f);
    #pragma unroll
    for (int g = 0; g < 4; ++g) {
      float4 t4 = *(const float4*)&red[g * 2048 + c * 256 + lane * 4];
      s.x += t4.x; s.y += t4.y; s.z += t4.z; s.w += t4.w;
    }
    const int obase = m0 + i * 16 + quad * 4;
    float4 bias = *(const float4*)(eb2 + obase);
    const int n = n0 + j * 16 + l15;
    float4 out;
    out.x = fmaxf(s.x + bias.x, 0.f);
    out.y = fmaxf(s.y + bias.y, 0.f);
    out.z = fmaxf(s.z + bias.z, 0.f);
    out.w = fmaxf(s.w + bias.w, 0.f);
    *(float4*)(h2c + (long)n * C2 + obase) = out;
  }
}

// ---------------- im2col for conv3 (k3,p1), fragment-packed bf16 hi/lo ----------
__global__ void k_h2x(const float* __restrict__ h2c, ushort* __restrict__ h2xph,
                      ushort* __restrict__ h2xpl) {
  int idx = blockIdx.x * 256 + threadIdx.x;
  const int total = NN * 1536;
  for (; idx < total; idx += gridDim.x * 256) {
    int grp = idx >> 9;
    int r = idx & 511;
    int e = r & 7, lane = r >> 3;
    int quad = lane >> 4, l15 = lane & 15;
    int nt = grp / 48, kt = grp - nt * 48;
    int n = nt * 16 + l15;
    int k = kt * 32 + quad * 8 + e;
    int ic = k / 3, j = k - ic * 3;
    int s2 = (n & 127) + j - 1;
    int b = n >> 7;
    float v = (s2 >= 0 && s2 < SS) ? h2c[(long)(b*SS + s2)*C2 + ic] : 0.f;
    uint bi = __float_as_uint(v);
    h2xph[idx] = (ushort)(bi >> 16);
    float rr = v - __uint_as_float(bi & 0xffff0000u);
    h2xpl[idx] = (ushort)(__float_as_uint(rr) >> 16);
  }
}

// ---------------- S1: h3 = ew3 . h2x^T + eb3 (fragment-packed everything) -------
__global__ __launch_bounds__(256) void gemm_h3(const ushort* __restrict__ aH,
    const ushort* __restrict__ aL, const ushort* __restrict__ bH,
    const ushort* __restrict__ bL, const float* __restrict__ eb3,
    ushort* __restrict__ h3ph, ushort* __restrict__ h3pl) {
  __shared__ __align__(16) float red[4 * 4096];   // 64 KB
  const int tid = threadIdx.x;
  const int w = tid >> 6, lane = tid & 63;
  const int l15 = lane & 15, quad = lane >> 4;
  // XCD-aware swizzle: 448 blocks = 8 xcd x 14 m-chunks x 4 n-chunks
  const int bid = blockIdx.x;
  const int xcd = bid & 7, q = bid >> 3;
  const int mchunk = xcd * 14 + (q >> 2);
  const int nchunk = q & 3;
  const int mtL0 = mchunk * 4, nt0 = nchunk * 4, n0 = nchunk * 64;
  const int kt0 = w * 12;
  f32x4 acc[4][4] = {};
  const ushort* aHB = aH + ((long)(mtL0 * 48 + kt0)) * 512 + lane * 8;
  const ushort* aLB = aL + ((long)(mtL0 * 48 + kt0)) * 512 + lane * 8;
  const ushort* bHB = bH + ((long)(nt0 * 48 + kt0)) * 512 + lane * 8;
  const ushort* bLB = bL + ((long)(nt0 * 48 + kt0)) * 512 + lane * 8;
  for (int kt = 0; kt < 12; ++kt) {
    short8 ah[4], al[4], bh[4], bl[4];
    #pragma unroll
    for (int f = 0; f < 4; ++f) {
      long o = ((long)(f * 48 + kt)) * 512;
      ah[f] = *(const short8*)(aHB + o);
      al[f] = *(const short8*)(aLB + o);
      bh[f] = *(const short8*)(bHB + o);
      bl[f] = *(const short8*)(bLB + o);
    }
    #pragma unroll
    for (int i = 0; i < 4; ++i)
      #pragma unroll
      for (int j = 0; j < 4; ++j) {
        acc[i][j] = __builtin_amdgcn_mfma_f32_16x16x32_bf16(ah[i], bh[j], acc[i][j], 0, 0, 0);
        acc[i][j] = __builtin_amdgcn_mfma_f32_16x16x32_bf16(ah[i], bl[j], acc[i][j], 0, 0, 0);
        acc[i][j] = __builtin_amdgcn_mfma_f32_16x16x32_bf16(al[i], bh[j], acc[i][j], 0, 0, 0);
      }
  }
  #pragma unroll
  for (int i = 0; i < 4; ++i)
    #pragma unroll
    for (int j = 0; j < 4; ++j)
      *(float4*)&red[w * 4096 + (i * 4 + j) * 256 + lane * 4] = *(float4*)&acc[i][j];
  __syncthreads();
  const int mg0 = mchunk * 64 + w * 16 + quad * 4;
  float4 bias = *(const float4*)(eb3 + mg0);
  const int ktS = mg0 >> 5, quadk = (mg0 >> 3) & 3, es = mg0 & 7;
  #pragma unroll
  for (int j = 0; j < 4; ++j) {
    float4 s = *(const float4*)&red[(w * 4 + j) * 256 + lane * 4];
    #pragma unroll
    for (int r = 1; r < 4; ++r) {
      float4 tt = *(const float4*)&red[r * 4096 + (w * 4 + j) * 256 + lane * 4];
      s.x += tt.x; s.y += tt.y; s.z += tt.z; s.w += tt.w;
    }
    const int n = n0 + j * 16 + l15;
    float v0 = s.x + bias.x;
    float v1 = s.y + bias.y;
    float v2 = s.z + bias.z;
    float v3 = s.w + bias.w;
    uint b0 = __float_as_uint(v0), b1 = __float_as_uint(v1);
    uint b2 = __float_as_uint(v2), b3 = __float_as_uint(v3);
    uint2 hp;
    hp.x = (b0 >> 16) | (b1 & 0xffff0000u);
    hp.y = (b2 >> 16) | (b3 & 0xffff0000u);
    float r0 = v0 - __uint_as_float(b0 & 0xffff0000u);
    float r1 = v1 - __uint_as_float(b1 & 0xffff0000u);
    float r2 = v2 - __uint_as_float(b2 & 0xffff0000u);
    float r3 = v3 - __uint_as_float(b3 & 0xffff0000u);
    uint2 lp;
    lp.x = (__float_as_uint(r0) >> 16) | (__float_as_uint(r1) & 0xffff0000u);
    lp.y = (__float_as_uint(r2) >> 16) | (__float_as_uint(r3) & 0xffff0000u);
    long off = ((long)((n >> 4) * 224 + ktS)) * 512 + (quadk * 16 + (n & 15)) * 8 + es;
    *(uint2*)(h3ph + off) = hp;
    *(uint2*)(h3pl + off) = lp;
  }
}

// ---------------- S2: scores + FUSED partial argmin ----------
__global__ __launch_bounds__(256) void gemm_scores(const ushort* __restrict__ aH,
    const ushort* __restrict__ aL, const ushort* __restrict__ bH,
    const ushort* __restrict__ bL, const float* __restrict__ cbn,
    float* __restrict__ pval, int* __restrict__ pidx) {
  __shared__ __align__(16) float red[4 * 4096];   // 64 KB
  __shared__ float wv_[4 * 64];
  __shared__ int   wi_[4 * 64];
  const int tid = threadIdx.x;
  const int w = tid >> 6, lane = tid & 63;
  const int l15 = lane & 15, quad = lane >> 4;
  const int m0 = blockIdx.x * 64, n0 = blockIdx.y * 64, z = blockIdx.z;
  const int mt0 = blockIdx.x * 4;
  const int kt0 = w * 4;
  f32x4 acc[4][4] = {};
  const ushort* aHB = aH + ((long)((z * 64 + mt0) * 16 + kt0)) * 512 + lane * 8;
  const ushort* aLB = aL + ((long)((z * 64 + mt0) * 16 + kt0)) * 512 + lane * 8;
  const ushort* bHB = bH + ((long)((n0 >> 4) * 224 + z * 16 + kt0)) * 512 + lane * 8;
  const ushort* bLB = bL + ((long)((n0 >> 4) * 224 + z * 16 + kt0)) * 512 + lane * 8;
  for (int kt = 0; kt < 4; ++kt) {
    short8 ah[4], al[4], bh[4], bl[4];
    #pragma unroll
    for (int f = 0; f < 4; ++f) {
      long oa = ((long)(f * 16 + kt)) * 512;
      long ob = ((long)(f * 224 + kt)) * 512;
      ah[f] = *(const short8*)(aHB + oa);
      al[f] = *(const short8*)(aLB + oa);
      bh[f] = *(const short8*)(bHB + ob);
      bl[f] = *(const short8*)(bLB + ob);
    }
    #pragma unroll
    for (int i = 0; i < 4; ++i)
      #pragma unroll
      for (int j = 0; j < 4; ++j) {
        acc[i][j] = __builtin_amdgcn_mfma_f32_16x16x32_bf16(ah[i], bh[j], acc[i][j], 0, 0, 0);
        acc[i][j] = __builtin_amdgcn_mfma_f32_16x16x32_bf16(ah[i], bl[j], acc[i][j], 0, 0, 0);
        acc[i][j] = __builtin_amdgcn_mfma_f32_16x16x32_bf16(al[i], bh[j], acc[i][j], 0, 0, 0);
      }
  }
  #pragma unroll
  for (int i = 0; i < 4; ++i)
    #pragma unroll
    for (int j = 0; j < 4; ++j)
      *(float4*)&red[w * 4096 + (i * 4 + j) * 256 + lane * 4] = *(float4*)&acc[i][j];
  __syncthreads();
  const int vbase = m0 + w * 16 + quad * 4;
  float4 cn = *(const float4*)(cbn + z * VOC + vbase);
  #pragma unroll
  for (int j = 0; j < 4; ++j) {
    float4 s = *(const float4*)&red[(w * 4 + j) * 256 + lane * 4];
    #pragma unroll
    for (int r = 1; r < 4; ++r) {
      float4 tt = *(const float4*)&red[r * 4096 + (w * 4 + j) * 256 + lane * 4];
      s.x += tt.x; s.y += tt.y; s.z += tt.z; s.w += tt.w;
    }
    float o0 = cn.x - 2.f * s.x;
    float o1 = cn.y - 2.f * s.y;
    float o2 = cn.z - 2.f * s.z;
    float o3 = cn.w - 2.f * s.w;
    float bv = o0; int bm = vbase;
    if (o1 < bv) { bv = o1; bm = vbase + 1; }
    if (o2 < bv) { bv = o2; bm = vbase + 2; }
    if (o3 < bv) { bv = o3; bm = vbase + 3; }
    #pragma unroll
    for (int off = 16; off <= 32; off <<= 1) {
      float ov = __shfl_xor(bv, off);
      int om = __shfl_xor(bm, off);
      if (ov < bv || (ov == bv && om < bm)) { bv = ov; bm = om; }
    }
    if (quad == 0) { wv_[w * 64 + j * 16 + l15] = bv; wi_[w * 64 + j * 16 + l15] = bm; }
  }
  __syncthreads();
  if (tid < 64) {
    float bv = wv_[tid]; int bm = wi_[tid];
    #pragma unroll
    for (int g = 1; g < 4; ++g) {
      float ov = wv_[g * 64 + tid]; int om = wi_[g * 64 + tid];
      if (ov < bv || (ov == bv && om < bm)) { bv = ov; bm = om; }
    }
    long prow = (long)z * NN + n0 + tid;
    pval[prow * 16 + blockIdx.x] = bv;
    pidx[prow * 16 + blockIdx.x] = bm;
  }
}

// ---------------- final argmin over the 16 m-chunk partials ----------------
__global__ void k_argmin2(const float* __restrict__ pval, const int* __restrict__ pidx,
                          int* __restrict__ codes) {
  int row = blockIdx.x * 256 + threadIdx.x;   // z*256+n, 3584 total
  if (row >= NCBK * NN) return;
  const float* pv = pval + (long)row * 16;
  const int*   pi = pidx + (long)row * 16;
  float bv = pv[0]; int bm = pi[0];
  #pragma unroll
  for (int c = 1; c < 16; ++c) {
    float v = pv[c]; int m = pi[c];
    if (v < bv || (v == bv && m < bm)) { bv = v; bm = m; }
  }
  codes[row] = bm;
}

// ---------------- gather q as bf16 fragments ----------------
__global__ void k_gather_qbf(const float* __restrict__ cb, const int* __restrict__ codes,
                             ushort* __restrict__ qp) {
  int o = blockIdx.x * 256 + threadIdx.x;
  const int total = NN * C3 / 8;                 // 229376
  if (o >= total) return;
  int frag = o >> 6, r = o & 63;
  int quad = r >> 4, l15 = r & 15;
  int nt = frag / 224, kt = frag - nt * 224;
  int n = nt * 16 + l15;
  int kglob = kt * 32 + quad * 8;
  int kcb = kglob >> 9, d0 = kglob & 511;
  int code = codes[kcb * NN + n];
  const float* s = cb + ((long)(kcb * VOC + code)) * DIMV + d0;
  float4 x0 = *(const float4*)s;
  float4 x1 = *(const float4*)(s + 4);
  uint4 u;
  u.x = (uint)f2bf(x0.x) | ((uint)f2bf(x0.y) << 16);
  u.y = (uint)f2bf(x0.z) | ((uint)f2bf(x0.w) << 16);
  u.z = (uint)f2bf(x1.x) | ((uint)f2bf(x1.y) << 16);
  u.w = (uint)f2bf(x1.z) | ((uint)f2bf(x1.w) << 16);
  ((uint4*)qp)[o] = u;
}

// ---------------- decoder convT GEMM via MFMA bf16 (fragment-packed) ----------------
// 16-wave blocks, disjoint K-1/16 per wave (14 kt), staged 4-round LDS reduce.
__global__ __launch_bounds__(1024) void gemm_a1_mfma(const ushort* __restrict__ dw1p,
    const ushort* __restrict__ qp, float* __restrict__ a1raw) {
  __shared__ __align__(16) float red[4 * 4096];
  const int tid = threadIdx.x;
  const int w = tid >> 6, lane = tid & 63;
  const int l15 = lane & 15, quad = lane >> 4;
  const int mt0 = blockIdx.x * 4, nt0 = blockIdx.y * 4;
  const int kt0 = w * 14;
  f32x4 acc[4][4] = {};
  const ushort* aB = dw1p + ((long)(mt0 * 224 + kt0)) * 512 + lane * 8;
  const ushort* bB = qp   + ((long)(nt0 * 224 + kt0)) * 512 + lane * 8;
  #pragma unroll 2
  for (int kt = 0; kt < 14; ++kt) {
    short8 ah[4], bh[4];
    #pragma unroll
    for (int f = 0; f < 4; ++f) {
      ah[f] = *(const short8*)(aB + ((long)(f * 224 + kt)) * 512);
      bh[f] = *(const short8*)(bB + ((long)(f * 224 + kt)) * 512);
    }
    #pragma unroll
    for (int i = 0; i < 4; ++i)
      #pragma unroll
      for (int j = 0; j < 4; ++j)
        acc[i][j] = __builtin_amdgcn_mfma_f32_16x16x32_bf16(ah[i], bh[j], acc[i][j], 0, 0, 0);
  }
  float4 rsum = make_float4(0.f, 0.f, 0.f, 0.f);
  #pragma unroll
  for (int r = 0; r < 4; ++r) {
    if ((w >> 2) == r) {
      #pragma unroll
      for (int i = 0; i < 4; ++i)
        #pragma unroll
        for (int j = 0; j < 4; ++j)
          *(float4*)&red[(w & 3) * 4096 + (i * 4 + j) * 256 + lane * 4] = *(float4*)&acc[i][j];
    }
    __syncthreads();
    #pragma unroll
    for (int g = 0; g < 4; ++g) {
      float4 t4 = *(const float4*)&red[g * 4096 + w * 256 + lane * 4];
      rsum.x += t4.x; rsum.y += t4.y; rsum.z += t4.z; rsum.w += t4.w;
    }
    __syncthreads();
  }
  const int ci = w >> 2, cj = w & 3;
  const int n = nt0 * 16 + cj * 16 + l15;
  const int mb = mt0 * 16 + ci * 16 + quad * 4;
  float v[4] = {rsum.x, rsum.y, rsum.z, rsum.w};
  #pragma unroll
  for (int reg = 0; reg < 4; ++reg) {
    int m = mb + reg;
    int c = m / 5, jj = m - c * 5;
    a1raw[((long)(n * 5 + jj)) * C2 + c] = v[reg];
  }
}

// ---------------- k_x2: build conv2 im2col X fragment-packed (bf16 hi/lo) -------
__global__ void k_x2(const float* __restrict__ a1raw, const float* __restrict__ ab1g,
                     const float* __restrict__ db1, ushort* __restrict__ Xh,
                     ushort* __restrict__ Xl) {
  int idx = blockIdx.x * 256 + threadIdx.x;
  const int total = 2304 * 2560;
  for (; idx < total; idx += gridDim.x * 256) {
    int grp = idx >> 9;
    int r = idx & 511;
    int e = r & 7, lane = r >> 3;
    int quad = lane >> 4, l15 = lane & 15;
    int nt = grp / 80, kt = grp - nt * 80;
    int nu = nt * 16 + l15;
    int ck = kt * 32 + quad * 8 + e;
    int n = nu / 9, u = nu - n * 9;
    int c = ck / 5, jj = ck - c * 5;
    int w = u + jj;
    int s = n & 127;
    int tc = HOP * s - 6 + w;
    float v;
    if (tc < 0 || tc > TOUT - 1) v = 0.f;
    else if (w >= 4 && w <= 8)
      v = fmaxf(db1[c] + a1raw[((long)(n * 5 + (w - 4))) * C2 + c], 0.f);
    else v = ab1g[c];
    uint bi = __float_as_uint(v);
    Xh[idx] = (ushort)(bi >> 16);
    float rr = v - __uint_as_float(bi & 0xffff0000u);
    Xl[idx] = (ushort)(__float_as_uint(rr) >> 16);
  }
}

// ---------------- decoder conv2 as GEMM: a2act = relu(db2 + dw2 . X^T) ----------
// Fragment-packed operands. 4-wave blocks, disjoint 20 kt per wave,
// barrier-free K-loop, LDS reduce epilogue. (Reverted from 16-wave: the only
// counter row for 16-wave showed 80 us / MfmaUtil 0.09% — artifact or real
// regression; 4-wave measured <=43 us in rounds 8-9.)
__global__ __launch_bounds__(256) void gemm_dec2(const ushort* __restrict__ aH,
    const ushort* __restrict__ aL, const ushort* __restrict__ bH,
    const ushort* __restrict__ bL, const float* __restrict__ db2,
    float* __restrict__ a2act) {
  __shared__ __align__(16) float red[4 * 4096];   // 64 KB
  const int tid = threadIdx.x;
  const int w = tid >> 6, lane = tid & 63;
  const int l15 = lane & 15, quad = lane >> 4;
  const int mt0 = blockIdx.x * 4, nt0 = blockIdx.y * 4;
  const int m0 = mt0 * 16, n0 = nt0 * 16;
  const int kt0 = w * 20;                     // disjoint 20 k-tiles per wave
  f32x4 acc[4][4] = {};
  const ushort* aHB = aH + ((long)(mt0 * 80 + kt0)) * 512 + lane * 8;
  const ushort* aLB = aL + ((long)(mt0 * 80 + kt0)) * 512 + lane * 8;
  const ushort* bHB = bH + ((long)(nt0 * 80 + kt0)) * 512 + lane * 8;
  const ushort* bLB = bL + ((long)(nt0 * 80 + kt0)) * 512 + lane * 8;
  for (int kt = 0; kt < 20; ++kt) {
    short8 ah[4], al[4], bh[4], bl[4];
    #pragma unroll
    for (int f = 0; f < 4; ++f) {
      long o = ((long)(f * 80 + kt)) * 512;
      ah[f] = *(const short8*)(aHB + o);
      al[f] = *(const short8*)(aLB + o);
      bh[f] = *(const short8*)(bHB + o);
      bl[f] = *(const short8*)(bLB + o);
    }
    #pragma unroll
    for (int i = 0; i < 4; ++i)
      #pragma unroll
      for (int j = 0; j < 4; ++j) {
        acc[i][j] = __builtin_amdgcn_mfma_f32_16x16x32_bf16(ah[i], bh[j], acc[i][j], 0, 0, 0);
        acc[i][j] = __builtin_amdgcn_mfma_f32_16x16x32_bf16(ah[i], bl[j], acc[i][j], 0, 0, 0);
        acc[i][j] = __builtin_amdgcn_mfma_f32_16x16x32_bf16(al[i], bh[j], acc[i][j], 0, 0, 0);
      }
  }
  // stash partials: region w, chunk (i*4+j), lane-contiguous float4 (2-way = free)
  #pragma unroll
  for (int i = 0; i < 4; ++i)
    #pragma unroll
    for (int j = 0; j < 4; ++j)
      *(float4*)&red[w * 4096 + (i * 4 + j) * 256 + lane * 4] = *(float4*)&acc[i][j];
  __syncthreads();
  // wave w reduces the 4 K-partials for row-block i=w, applies bias+relu, stores
  const int mb = m0 + w * 16 + quad * 4;
  float4 bias = *(const float4*)(db2 + mb);
  #pragma unroll
  for (int j = 0; j < 4; ++j) {
    float4 s = *(const float4*)&red[(w * 4 + j) * 256 + lane * 4];
    #pragma unroll
    for (int r = 1; r < 4; ++r) {
      float4 tt = *(const float4*)&red[r * 4096 + (w * 4 + j) * 256 + lane * 4];
      s.x += tt.x; s.y += tt.y; s.z += tt.z; s.w += tt.w;
    }
    const int nu = n0 + j * 16 + l15;
    float4 out;
    out.x = fmaxf(s.x + bias.x, 0.f);
    out.y = fmaxf(s.y + bias.y, 0.f);
    out.z = fmaxf(s.z + bias.z, 0.f);
    out.w = fmaxf(s.w + bias.w, 0.f);
    *(float4*)(a2act + (long)nu * C1 + mb) = out;
  }
}

// ---------------- decoder conv3+tanh + constant fill (merged) ----------------
// Block (b,s) owns output cols [768s-384, 768s+384) (clipped): computes the
// <=15 active cols via conv, fills the rest with the constant tanh value.
__global__ __launch_bounds__(256) void k_dec3(const float* __restrict__ a2act,
    const float* __restrict__ ab2g, const float* __restrict__ dw3,
    const float* __restrict__ db3, const float* __restrict__ cconst,
    float* __restrict__ outp) {
  __shared__ float sa2[9 * C1];
  __shared__ float sb[C1];
  int n = blockIdx.x;
  int s = n & 127, b = n >> 7;
  int t = threadIdx.x;
  for (int i = t; i < 9 * C1; i += 256) sa2[i] = a2act[(long)n * 9 * C1 + i];
  sb[t] = ab2g[t];
  __syncthreads();
  // fill owned non-active cols with the constant
  float vfill = cconst[0];
  int lo = (s == 0) ? 0 : HOP * s - 384;
  int hi = (s == SS - 1) ? TOUT : HOP * s + 384;
  for (int tc = lo + t; tc < hi; tc += 256) {
    int d = tc - HOP * s;
    if (d < -7 || d > 7) outp[(long)b * TOUT + tc] = vfill;
  }
  int wv = t >> 6, lane = t & 63;
  float b3 = db3[0];
  for (int w15 = wv; w15 < 15; w15 += 4) {
    int tc = HOP * s - 7 + w15;
    if (tc < 0 || tc > TOUT - 1) continue;
    float part = 0.f;
    for (int cc = lane; cc < C1; cc += 64) {
      #pragma unroll
      for (int j = 0; j < 7; ++j) {
        int wcol = tc + j - 3;
        float x;
        if (wcol < 0 || wcol > TOUT - 1) x = 0.f;
        else {
          int du = wcol - (HOP * s - 4);
          x = (du >= 0 && du <= 8) ? sa2[du * C1 + cc] : sb[cc];
        }
        part = fmaf(dw3[cc*7+j], x, part);
      }
    }
    for (int off = 32; off; off >>= 1) part += __shfl_down(part, off);
    if (lane == 0) outp[(long)b * TOUT + tc] = tanhf(part + b3);
  }
}

extern "C" void kernel_launch(void* const* d_in, const int* in_sizes, int n_in,
                              void* d_out, int out_size, void* d_ws, size_t ws_size,
                              hipStream_t stream) {
  const float* audio = (const float*)d_in[0];
  const float* cb    = (const float*)d_in[1];
  const float* ew1   = (const float*)d_in[2];
  const float* eb1   = (const float*)d_in[3];
  const float* ew2   = (const float*)d_in[4];
  const float* eb2   = (const float*)d_in[5];
  const float* ew3   = (const float*)d_in[6];
  const float* eb3   = (const float*)d_in[7];
  const float* dw1   = (const float*)d_in[8];
  const float* db1   = (const float*)d_in[9];
  const float* dw2   = (const float*)d_in[10];
  const float* db2   = (const float*)d_in[11];
  const float* dw3   = (const float*)d_in[12];
  const float* db3   = (const float*)d_in[13];
  float* outp = (float*)d_out;
  float* ws = (float*)d_ws;

  float*  cbn    = ws + OFF_CBN;
  float*  ab1    = ws + OFF_AB1;
  float*  ab2    = ws + OFF_AB2;
  float*  cconst = ws + OFF_CCONST;
  float*  h2c    = ws + OFF_H2C;
  ushort* h2xph  = (ushort*)(ws + OFF_H2XH);
  ushort* h2xpl  = (ushort*)(ws + OFF_H2XL);
  ushort* h3ph   = (ushort*)(ws + OFF_H3H);
  ushort* h3pl   = (ushort*)(ws + OFF_H3L);
  ushort* X1h    = (ushort*)(ws + OFF_X1H);
  ushort* X1l    = (ushort*)(ws + OFF_X1L);
  ushort* cbph   = (ushort*)(ws + OFF_CBPH);
  ushort* cbpl   = (ushort*)(ws + OFF_CBPL);
  ushort* ew3ph  = (ushort*)(ws + OFF_EW3PH);
  ushort* ew3pl  = (ushort*)(ws + OFF_EW3PL);
  ushort* ew2ph  = (ushort*)(ws + OFF_EW2PH);
  ushort* ew2pl  = (ushort*)(ws + OFF_EW2PL);
  float*  pval   = ws + OFF_PVAL;
  int*    pidx   = (int*)(ws + OFF_PIDX);
  ushort* dw1p   = (ushort*)(ws + OFF_DW1P);
  ushort* dw2ph  = (ushort*)(ws + OFF_DW2PH);
  ushort* dw2pl  = (ushort*)(ws + OFF_DW2PL);
  ushort* Xh     = (ushort*)(ws + OFF_XH);
  ushort* Xl     = (ushort*)(ws + OFF_XL);
  int*    codes  = (int*)(ws + OFF_CODES);
  ushort* qp     = (ushort*)(ws + OFF_QBF);
  float*  a1raw  = ws + OFF_A1RAW;
  float*  a2act  = ws + OFF_A2ACT;

  // all weight packs in one BW-saturating launch
  k_packw<<<7360, 256, 0, stream>>>(cb, ew2, ew3, dw2, dw1,
      cbph, cbpl, cbn, ew2ph, ew2pl, ew3ph, ew3pl, dw2ph, dw2pl, dw1p);
  k_prep_ab2<<<C1, 256, 0, stream>>>(db1, dw2, db2, ab1, ab2);
  k_prep_c<<<1, 256, 0, stream>>>(dw3, db3, ab2, cconst);
  k_enc1<<<NN, 256, 0, stream>>>(audio, ew1, eb1, X1h, X1l);
  gemm_enc2<<<dim3(16, 4), 256, 0, stream>>>(ew2ph, ew2pl, X1h, X1l, eb2, h2c);
  k_h2x<<<384, 256, 0, stream>>>(h2c, h2xph, h2xpl);
  gemm_h3<<<448, 256, 0, stream>>>(ew3ph, ew3pl, h2xph, h2xpl, eb3, h3ph, h3pl);
  gemm_scores<<<dim3(16, 4, 14), 256, 0, stream>>>(cbph, cbpl, h3ph, h3pl, cbn, pval, pidx);
  k_argmin2<<<14, 256, 0, stream>>>(pval, pidx, codes);
  k_gather_qbf<<<896, 256, 0, stream>>>(cb, codes, qp);
  gemm_a1_mfma<<<dim3(40, 4), 1024, 0, stream>>>(dw1p, qp, a1raw);
  // Xh/Xl overlap h3p/X1 (dead after gemm_scores) — stream-ordered after gemm_a1
  k_x2<<<4096, 256, 0, stream>>>(a1raw, ab1, db1, Xh, Xl);
  gemm_dec2<<<dim3(4, 36), 256, 0, stream>>>(dw2ph, dw2pl, Xh, Xl, db2, a2act);
  k_dec3<<<NN, 256, 0, stream>>>(a2act, ab2, dw3, db3, cconst, outp);
}

// Round 13
// 376.607 us; speedup vs baseline: 1.0383x; 1.0029x over previous
//
#include <hip/hip_runtime.h>
#include <hip/hip_bf16.h>
#include <math.h>

#define T_IN 98304
#define SS 128
#define NBATCH 2
#define NN 256          // NBATCH*SS
#define C1 256
#define C2 512
#define C3 7168
#define NCBK 14
#define DIMV 512
#define VOC 1024
#define TOUT 97537
#define HOP 768

// ws layout (float offsets). Harness allocates ~280 MB ws; fresh space beyond
// 11880720 confirmed usable (rounds 7-12). This layout uses ~163 MB.
#define OFF_CBN    0L          // 14336
#define OFF_AB1    14336L      // 512
#define OFF_AB2    14848L      // 256
#define OFF_CCONST 15104L      // 16
#define OFF_H2C    15120L      // 131072   (n*512+ic), n=b*128+s
// h2xp: fragment-packed bf16 [16 nt][48 kt][512] per plane (196608 fl each)
#define OFF_H2XH   146192L     // ends 342800
#define OFF_H2XL   342800L     // ends 539408
// h3p: fragment-packed bf16 (B-operand layout for gemm_scores)
#define OFF_H3H    539408L     // ends 1456912
#define OFF_H3L    1456912L    // ends 2374416
// X1p fragment-packed bf16 [16 nt][40 kt][512] (163840 fl each)
#define OFF_X1H    2374416L    // ends 2538256
#define OFF_X1L    2538256L    // ends 2702096
// Xp hi/lo fragment-packed [144 nt][80 kt][512] per plane (2949120 fl each)
// OVERLAP h3p/X1 (dead after gemm_scores; k_x2 launches after gemm_a1).
#define OFF_XH     539408L     // ends 3488528
#define OFF_XL     3488528L    // ends 6437648
#define OFF_CODES  9714448L    // 3584 ints
#define OFF_QBF    9718032L    // 917504 fl (bf16 fragment-packed [16 nt][224 kt][512])
#define OFF_A1RAW  10635536L   // 655360   ((n*5+j)*512 + c)  pre-bias/relu
#define OFF_A2ACT  11290896L   // 589824   ((n*9+u)*256 + o)  post-relu
// ---- fresh space (no aliasing) ----
#define OFF_CBPH   11880720L   // ends 15550736
#define OFF_CBPL   15550736L   // ends 19220752
#define OFF_EW3PH  19220752L   // ends 24725776
#define OFF_EW3PL  24725776L   // ends 30230800
#define OFF_EW2PH  30230800L   // ends 30558480
#define OFF_EW2PL  30558480L   // ends 30886160
#define OFF_PVAL   30886160L   // ends 30943504
#define OFF_PIDX   30943504L   // ends 31000848
#define OFF_DW1P   31000848L   // ends 40175888  (bf16 [160 mt][224 kt][512])
#define OFF_DW2PH  40175888L   // ends 40503568  (bf16 [16 mt][80 kt][512])
#define OFF_DW2PL  40503568L   // ends 40831248
// total ~163.3 MB

typedef __attribute__((ext_vector_type(8))) short short8;
typedef __attribute__((ext_vector_type(4))) float f32x4;

static __device__ inline ushort f2bf(float x) {
  __hip_bfloat16 h = __float2bfloat16(x);
  return *reinterpret_cast<ushort*>(&h);
}

// exact 2-term split: x = hi + lo + O(2^-16 |x|); truncation split, residual exact
static __device__ inline void split8(const float4 x0, const float4 x1,
                                     short8& h, short8& l) {
  float xs[8] = {x0.x, x0.y, x0.z, x0.w, x1.x, x1.y, x1.z, x1.w};
  #pragma unroll
  for (int e = 0; e < 8; ++e) {
    uint b = __float_as_uint(xs[e]);
    h[e] = (short)(b >> 16);
    float r = xs[e] - __uint_as_float(b & 0xffff0000u);
    l[e] = (short)(__float_as_uint(r) >> 16);
  }
}

// ---------------- ONE pack kernel for all weights ----------------
// Sections by blockIdx.x:
//  [0,896)      : cb -> cbp hi/lo + row norms (zmt = bid)
//  [896,1216)   : ew2 -> ew2p
//  [1216,2560)  : ew3 -> ew3p (4 units/thread)
//  [2560,2880)  : dw2 -> dw2p
//  [2880,7360)  : dw1 -> dw1p. Fragment-ordered LDS staging so the GLOBAL
//                 writes are wave-linear (1 KB contiguous per wave). Old
//                 version wrote scattered 16 B granules -> 2.6 TB/s kernel.
__global__ __launch_bounds__(256) void k_packw(const float* __restrict__ cb,
    const float* __restrict__ ew2, const float* __restrict__ ew3,
    const float* __restrict__ dw2, const float* __restrict__ dw1,
    ushort* __restrict__ cbph, ushort* __restrict__ cbpl, float* __restrict__ cbn,
    ushort* __restrict__ ew2ph, ushort* __restrict__ ew2pl,
    ushort* __restrict__ ew3ph, ushort* __restrict__ ew3pl,
    ushort* __restrict__ dw2ph, ushort* __restrict__ dw2pl,
    ushort* __restrict__ dw1p) {
  __shared__ __align__(16) ushort T[4608];
  __shared__ float red[256];
  const int bid = blockIdx.x;
  const int t = threadIdx.x;
  if (bid < 896) {
    // ---- cbp + norms ----
    int zmt = bid;
    int lane = t & 63, fg = t >> 6;
    int quad = lane >> 4, l15 = lane & 15;
    int row = zmt * 16 + l15;
    float ss = 0.f;
    #pragma unroll
    for (int h = 0; h < 4; ++h) {
      int kt = fg * 4 + h;
      int k = kt * 32 + quad * 8;
      const float* s = cb + (long)row * DIMV + k;
      float4 x0 = *(const float4*)s;
      float4 x1 = *(const float4*)(s + 4);
      short8 hh, ll;
      split8(x0, x1, hh, ll);
      long off = ((long)zmt * 16 + kt) * 512 + lane * 8;
      *(short8*)(cbph + off) = hh;
      *(short8*)(cbpl + off) = ll;
      ss += x0.x*x0.x + x0.y*x0.y + x0.z*x0.z + x0.w*x0.w
          + x1.x*x1.x + x1.y*x1.y + x1.z*x1.z + x1.w*x1.w;
    }
    red[t] = ss;
    __syncthreads();
    if (t < 16) {
      float s = 0.f;
      #pragma unroll
      for (int g = 0; g < 16; ++g) s += red[t + g * 16];
      cbn[zmt * 16 + t] = s;
    }
  } else if (bid < 1216) {
    // ---- ew2p ----
    int o8 = (bid - 896) * 256 + t;            // < 81920
    int frag = o8 >> 6, lane = o8 & 63;
    int quad = lane >> 4, l15 = lane & 15;
    int mt = frag / 40, kt = frag - mt * 40;
    const float* s = ew2 + (long)(mt * 16 + l15) * 1280 + kt * 32 + quad * 8;
    float4 x0 = *(const float4*)s;
    float4 x1 = *(const float4*)(s + 4);
    short8 h, l;
    split8(x0, x1, h, l);
    long off = (long)o8 * 8;
    *(short8*)(ew2ph + off) = h;
    *(short8*)(ew2pl + off) = l;
  } else if (bid < 2560) {
    // ---- ew3p: 4 independent units per thread ----
    int u0 = (bid - 1216) * 1024 + t;          // 1344 blocks x 1024 units
    #pragma unroll
    for (int i = 0; i < 4; ++i) {
      int o8 = u0 + i * 256;                   // < 1376256
      int frag = o8 >> 6, lane = o8 & 63;
      int quad = lane >> 4, l15 = lane & 15;
      int mtL = frag / 48, kt = frag - mtL * 48;
      const float* s = ew3 + (long)(mtL * 16 + l15) * 1536 + kt * 32 + quad * 8;
      float4 x0 = *(const float4*)s;
      float4 x1 = *(const float4*)(s + 4);
      short8 h, l;
      split8(x0, x1, h, l);
      long off = (long)o8 * 8;
      *(short8*)(ew3ph + off) = h;
      *(short8*)(ew3pl + off) = l;
    }
  } else if (bid < 2880) {
    // ---- dw2p ----
    int o8 = (bid - 2560) * 256 + t;           // < 81920
    int frag = o8 >> 6, lane = o8 & 63;
    int quad = lane >> 4, l15 = lane & 15;
    int mt = frag / 80, kt = frag - mt * 80;
    const float* s = dw2 + (long)(mt * 16 + l15) * 2560 + kt * 32 + quad * 8;
    float4 x0 = *(const float4*)s;
    float4 x1 = *(const float4*)(s + 4);
    short8 h, l;
    split8(x0, x1, h, l);
    long off = (long)o8 * 8;
    *(short8*)(dw2ph + off) = h;
    *(short8*)(dw2pl + off) = l;
  } else {
    // ---- dw1t: [7168][2560] fp32 -> fragment-packed bf16, 64x64 tile ----
    // Stage into LDS in FRAGMENT order (8 fragments x 512 ushorts), then
    // write out linearly: each wave emits one contiguous 1 KB fragment.
    int idx = bid - 2880;                      // < 4480
    int kb = idx / 40, mb = idx - kb * 40;
    int k0 = kb * 64, m0 = mb * 64;
    int kk = t >> 2, mj = (t & 3) * 16;
    const float* src = dw1 + (long)(k0 + kk) * 2560 + m0 + mj;
    float x[16];
    *(float4*)&x[0]  = *(const float4*)(src);
    *(float4*)&x[4]  = *(const float4*)(src + 4);
    *(float4*)&x[8]  = *(const float4*)(src + 8);
    *(float4*)&x[12] = *(const float4*)(src + 12);
    const int quad = (kk >> 3) & 3, e = kk & 7, ktl = kk >> 5;
    #pragma unroll
    for (int l = 0; l < 16; ++l) {
      int m_local = mj + l;
      int f = ((m_local >> 4) << 1) | ktl;     // fragment 0..7 (mt_local*2 + kt_local)
      T[f * 512 + (quad * 16 + (m_local & 15)) * 8 + e] = f2bf(x[l]);
    }
    __syncthreads();
    const int mtB = m0 >> 4, ktB = k0 >> 5;
    #pragma unroll
    for (int r = 0; r < 2; ++r) {
      int u = r * 256 + t;                     // uint4 index 0..511
      int f = u >> 6;                          // 64 uint4 per fragment
      int pos = (u & 63) * 8;                  // ushort offset in fragment
      int mt = mtB + (f >> 1);
      int kt = ktB + (f & 1);
      uint4 v = *(const uint4*)&T[f * 512 + pos];
      *(uint4*)(dw1p + ((long)(mt * 224 + kt)) * 512 + pos) = v;
    }
  }
}

// ---------------- prep A: ab1 = relu(db1); ab2[o] = relu(db2[o]+sum_c W(o,c)*ab1[c])
__global__ __launch_bounds__(256) void k_prep_ab2(const float* __restrict__ db1,
    const float* __restrict__ dw2, const float* __restrict__ db2,
    float* __restrict__ ab1, float* __restrict__ ab2) {
  __shared__ float red[256];
  int o = blockIdx.x, t = threadIdx.x;
  if (o == 0) { ab1[t] = fmaxf(db1[t], 0.f); ab1[t + 256] = fmaxf(db1[t + 256], 0.f); }
  const float* wp = dw2 + (long)o * C2 * 5;
  float acc = 0.f;
  #pragma unroll
  for (int h = 0; h < 2; ++h) {
    int c = t + h * 256;
    const float* p = wp + c * 5;
    float wsum = p[0] + p[1] + p[2] + p[3] + p[4];
    acc = fmaf(wsum, fmaxf(db1[c], 0.f), acc);
  }
  red[t] = acc;
  __syncthreads();
  for (int off = 128; off; off >>= 1) {
    if (t < off) red[t] += red[t + off];
    __syncthreads();
  }
  if (t == 0) ab2[o] = fmaxf(red[0] + db2[o], 0.f);
}

// ---------------- prep B: cconst = tanh(db3 + sum_o (sum_j dw3[o][j]) * ab2[o]) ----
__global__ __launch_bounds__(256) void k_prep_c(const float* __restrict__ dw3,
    const float* __restrict__ db3, const float* __restrict__ ab2,
    float* __restrict__ cconst) {
  __shared__ float red[256];
  int t = threadIdx.x;
  float wsum3 = 0.f;
  #pragma unroll
  for (int j = 0; j < 7; ++j) wsum3 += dw3[t*7+j];
  red[t] = wsum3 * ab2[t];
  __syncthreads();
  for (int off = 128; off; off >>= 1) {
    if (t < off) red[t] += red[t + off];
    __syncthreads();
  }
  if (t == 0) cconst[0] = tanhf(red[0] + db3[0]);
}

// ---------------- encoder conv1 (k7,p3) at the 5 cols conv2 needs ----------------
// Output written fragment-packed: X1p[(nt*40+kt)*512 + (quadk*16 + n&15)*8 + k&7]
__global__ __launch_bounds__(256) void k_enc1(const float* __restrict__ audio,
    const float* __restrict__ ew1, const float* __restrict__ eb1,
    ushort* __restrict__ X1h, ushort* __restrict__ X1l) {
  int n = blockIdx.x, ic = threadIdx.x;
  int b = n >> 7, s = n & 127;
  const float* ap = audio + (long)b * T_IN;
  int base = HOP * s - 5;           // audio idx for window pos 0
  float a[11];
  #pragma unroll
  for (int w = 0; w < 11; ++w) {
    int ai = base + w;
    a[w] = (ai >= 0 && ai < T_IN) ? ap[ai] : 0.f;
  }
  float w1[7];
  #pragma unroll
  for (int j = 0; j < 7; ++j) w1[j] = ew1[ic*7+j];
  float b1 = eb1[ic];
  #pragma unroll
  for (int jj = 0; jj < 5; ++jj) {
    int tcol = HOP * s + jj - 2;
    float v = 0.f;
    if (tcol >= 0) {
      float acc = b1;
      #pragma unroll
      for (int j = 0; j < 7; ++j) acc = fmaf(w1[j], a[jj + j], acc);
      v = fmaxf(acc, 0.f);
    }
    int k = ic * 5 + jj;
    int kt = k >> 5;
    int lane2 = ((k >> 3) & 3) * 16 + (n & 15);
    long idx = ((long)((n >> 4) * 40 + kt)) * 512 + lane2 * 8 + (k & 7);
    uint bi = __float_as_uint(v);
    X1h[idx] = (ushort)(bi >> 16);
    float r = v - __uint_as_float(bi & 0xffff0000u);
    X1l[idx] = (ushort)(__float_as_uint(r) >> 16);
  }
}

// ---------------- encoder conv2 as GEMM: h2c[n][oc] = relu(eb2 + ew2 . X1^T) ------
// Fragment-packed operands, 4-wave blocks, disjoint 10 kt per wave, barrier-free
// K-loop, LDS reduce epilogue.
__global__ __launch_bounds__(256) void gemm_enc2(const ushort* __restrict__ aH,
    const ushort* __restrict__ aL, const ushort* __restrict__ bH,
    const ushort* __restrict__ bL, const float* __restrict__ eb2,
    float* __restrict__ h2c) {
  __shared__ __align__(16) float red[4 * 2048];   // 32 KB
  const int tid = threadIdx.x;
  const int w = tid >> 6, lane = tid & 63;
  const int l15 = lane & 15, quad = lane >> 4;
  const int m0 = blockIdx.x * 32, n0 = blockIdx.y * 64;
  const int mt0 = blockIdx.x * 2, nt0 = blockIdx.y * 4;
  const int kt0 = w * 10;
  f32x4 acc[2][4] = {};
  const ushort* aHB = aH + ((long)(mt0 * 40 + kt0)) * 512 + lane * 8;
  const ushort* aLB = aL + ((long)(mt0 * 40 + kt0)) * 512 + lane * 8;
  const ushort* bHB = bH + ((long)(nt0 * 40 + kt0)) * 512 + lane * 8;
  const ushort* bLB = bL + ((long)(nt0 * 40 + kt0)) * 512 + lane * 8;
  for (int kt = 0; kt < 10; ++kt) {
    short8 ah[2], al[2], bh[4], bl[4];
    #pragma unroll
    for (int i = 0; i < 2; ++i) {
      long o = ((long)(i * 40 + kt)) * 512;
      ah[i] = *(const short8*)(aHB + o);
      al[i] = *(const short8*)(aLB + o);
    }
    #pragma unroll
    for (int f = 0; f < 4; ++f) {
      long o = ((long)(f * 40 + kt)) * 512;
      bh[f] = *(const short8*)(bHB + o);
      bl[f] = *(const short8*)(bLB + o);
    }
    #pragma unroll
    for (int i = 0; i < 2; ++i)
      #pragma unroll
      for (int j = 0; j < 4; ++j) {
        acc[i][j] = __builtin_amdgcn_mfma_f32_16x16x32_bf16(ah[i], bh[j], acc[i][j], 0, 0, 0);
        acc[i][j] = __builtin_amdgcn_mfma_f32_16x16x32_bf16(ah[i], bl[j], acc[i][j], 0, 0, 0);
        acc[i][j] = __builtin_amdgcn_mfma_f32_16x16x32_bf16(al[i], bh[j], acc[i][j], 0, 0, 0);
      }
  }
  #pragma unroll
  for (int i = 0; i < 2; ++i)
    #pragma unroll
    for (int j = 0; j < 4; ++j)
      *(float4*)&red[w * 2048 + (i * 4 + j) * 256 + lane * 4] = *(float4*)&acc[i][j];
  __syncthreads();
  #pragma unroll
  for (int q = 0; q < 2; ++q) {
    const int c = 2 * w + q;
    const int i = c >> 2, j = c & 3;
    float4 s = make_float4(0.f, 0.f, 0.f, 0.f);
    #pragma unroll
    for (int g = 0; g < 4; ++g) {
      float4 t4 = *(const float4*)&red[g * 2048 + c * 256 + lane * 4];
      s.x += t4.x; s.y += t4.y; s.z += t4.z; s.w += t4.w;
    }
    const int obase = m0 + i * 16 + quad * 4;
    float4 bias = *(const float4*)(eb2 + obase);
    const int n = n0 + j * 16 + l15;
    float4 out;
    out.x = fmaxf(s.x + bias.x, 0.f);
    out.y = fmaxf(s.y + bias.y, 0.f);
    out.z = fmaxf(s.z + bias.z, 0.f);
    out.w = fmaxf(s.w + bias.w, 0.f);
    *(float4*)(h2c + (long)n * C2 + obase) = out;
  }
}

// ---------------- im2col for conv3 (k3,p1), fragment-packed bf16 hi/lo ----------
__global__ void k_h2x(const float* __restrict__ h2c, ushort* __restrict__ h2xph,
                      ushort* __restrict__ h2xpl) {
  int idx = blockIdx.x * 256 + threadIdx.x;
  const int total = NN * 1536;
  for (; idx < total; idx += gridDim.x * 256) {
    int grp = idx >> 9;
    int r = idx & 511;
    int e = r & 7, lane = r >> 3;
    int quad = lane >> 4, l15 = lane & 15;
    int nt = grp / 48, kt = grp - nt * 48;
    int n = nt * 16 + l15;
    int k = kt * 32 + quad * 8 + e;
    int ic = k / 3, j = k - ic * 3;
    int s2 = (n & 127) + j - 1;
    int b = n >> 7;
    float v = (s2 >= 0 && s2 < SS) ? h2c[(long)(b*SS + s2)*C2 + ic] : 0.f;
    uint bi = __float_as_uint(v);
    h2xph[idx] = (ushort)(bi >> 16);
    float rr = v - __uint_as_float(bi & 0xffff0000u);
    h2xpl[idx] = (ushort)(__float_as_uint(rr) >> 16);
  }
}

// ---------------- S1: h3 = ew3 . h2x^T + eb3 (fragment-packed everything) -------
__global__ __launch_bounds__(256) void gemm_h3(const ushort* __restrict__ aH,
    const ushort* __restrict__ aL, const ushort* __restrict__ bH,
    const ushort* __restrict__ bL, const float* __restrict__ eb3,
    ushort* __restrict__ h3ph, ushort* __restrict__ h3pl) {
  __shared__ __align__(16) float red[4 * 4096];   // 64 KB
  const int tid = threadIdx.x;
  const int w = tid >> 6, lane = tid & 63;
  const int l15 = lane & 15, quad = lane >> 4;
  // XCD-aware swizzle: 448 blocks = 8 xcd x 14 m-chunks x 4 n-chunks
  const int bid = blockIdx.x;
  const int xcd = bid & 7, q = bid >> 3;
  const int mchunk = xcd * 14 + (q >> 2);
  const int nchunk = q & 3;
  const int mtL0 = mchunk * 4, nt0 = nchunk * 4, n0 = nchunk * 64;
  const int kt0 = w * 12;
  f32x4 acc[4][4] = {};
  const ushort* aHB = aH + ((long)(mtL0 * 48 + kt0)) * 512 + lane * 8;
  const ushort* aLB = aL + ((long)(mtL0 * 48 + kt0)) * 512 + lane * 8;
  const ushort* bHB = bH + ((long)(nt0 * 48 + kt0)) * 512 + lane * 8;
  const ushort* bLB = bL + ((long)(nt0 * 48 + kt0)) * 512 + lane * 8;
  for (int kt = 0; kt < 12; ++kt) {
    short8 ah[4], al[4], bh[4], bl[4];
    #pragma unroll
    for (int f = 0; f < 4; ++f) {
      long o = ((long)(f * 48 + kt)) * 512;
      ah[f] = *(const short8*)(aHB + o);
      al[f] = *(const short8*)(aLB + o);
      bh[f] = *(const short8*)(bHB + o);
      bl[f] = *(const short8*)(bLB + o);
    }
    #pragma unroll
    for (int i = 0; i < 4; ++i)
      #pragma unroll
      for (int j = 0; j < 4; ++j) {
        acc[i][j] = __builtin_amdgcn_mfma_f32_16x16x32_bf16(ah[i], bh[j], acc[i][j], 0, 0, 0);
        acc[i][j] = __builtin_amdgcn_mfma_f32_16x16x32_bf16(ah[i], bl[j], acc[i][j], 0, 0, 0);
        acc[i][j] = __builtin_amdgcn_mfma_f32_16x16x32_bf16(al[i], bh[j], acc[i][j], 0, 0, 0);
      }
  }
  #pragma unroll
  for (int i = 0; i < 4; ++i)
    #pragma unroll
    for (int j = 0; j < 4; ++j)
      *(float4*)&red[w * 4096 + (i * 4 + j) * 256 + lane * 4] = *(float4*)&acc[i][j];
  __syncthreads();
  const int mg0 = mchunk * 64 + w * 16 + quad * 4;
  float4 bias = *(const float4*)(eb3 + mg0);
  const int ktS = mg0 >> 5, quadk = (mg0 >> 3) & 3, es = mg0 & 7;
  #pragma unroll
  for (int j = 0; j < 4; ++j) {
    float4 s = *(const float4*)&red[(w * 4 + j) * 256 + lane * 4];
    #pragma unroll
    for (int r = 1; r < 4; ++r) {
      float4 tt = *(const float4*)&red[r * 4096 + (w * 4 + j) * 256 + lane * 4];
      s.x += tt.x; s.y += tt.y; s.z += tt.z; s.w += tt.w;
    }
    const int n = n0 + j * 16 + l15;
    float v0 = s.x + bias.x;
    float v1 = s.y + bias.y;
    float v2 = s.z + bias.z;
    float v3 = s.w + bias.w;
    uint b0 = __float_as_uint(v0), b1 = __float_as_uint(v1);
    uint b2 = __float_as_uint(v2), b3 = __float_as_uint(v3);
    uint2 hp;
    hp.x = (b0 >> 16) | (b1 & 0xffff0000u);
    hp.y = (b2 >> 16) | (b3 & 0xffff0000u);
    float r0 = v0 - __uint_as_float(b0 & 0xffff0000u);
    float r1 = v1 - __uint_as_float(b1 & 0xffff0000u);
    float r2 = v2 - __uint_as_float(b2 & 0xffff0000u);
    float r3 = v3 - __uint_as_float(b3 & 0xffff0000u);
    uint2 lp;
    lp.x = (__float_as_uint(r0) >> 16) | (__float_as_uint(r1) & 0xffff0000u);
    lp.y = (__float_as_uint(r2) >> 16) | (__float_as_uint(r3) & 0xffff0000u);
    long off = ((long)((n >> 4) * 224 + ktS)) * 512 + (quadk * 16 + (n & 15)) * 8 + es;
    *(uint2*)(h3ph + off) = hp;
    *(uint2*)(h3pl + off) = lp;
  }
}

// ---------------- S2: scores + FUSED partial argmin ----------
__global__ __launch_bounds__(256) void gemm_scores(const ushort* __restrict__ aH,
    const ushort* __restrict__ aL, const ushort* __restrict__ bH,
    const ushort* __restrict__ bL, const float* __restrict__ cbn,
    float* __restrict__ pval, int* __restrict__ pidx) {
  __shared__ __align__(16) float red[4 * 4096];   // 64 KB
  __shared__ float wv_[4 * 64];
  __shared__ int   wi_[4 * 64];
  const int tid = threadIdx.x;
  const int w = tid >> 6, lane = tid & 63;
  const int l15 = lane & 15, quad = lane >> 4;
  const int m0 = blockIdx.x * 64, n0 = blockIdx.y * 64, z = blockIdx.z;
  const int mt0 = blockIdx.x * 4;
  const int kt0 = w * 4;
  f32x4 acc[4][4] = {};
  const ushort* aHB = aH + ((long)((z * 64 + mt0) * 16 + kt0)) * 512 + lane * 8;
  const ushort* aLB = aL + ((long)((z * 64 + mt0) * 16 + kt0)) * 512 + lane * 8;
  const ushort* bHB = bH + ((long)((n0 >> 4) * 224 + z * 16 + kt0)) * 512 + lane * 8;
  const ushort* bLB = bL + ((long)((n0 >> 4) * 224 + z * 16 + kt0)) * 512 + lane * 8;
  for (int kt = 0; kt < 4; ++kt) {
    short8 ah[4], al[4], bh[4], bl[4];
    #pragma unroll
    for (int f = 0; f < 4; ++f) {
      long oa = ((long)(f * 16 + kt)) * 512;
      long ob = ((long)(f * 224 + kt)) * 512;
      ah[f] = *(const short8*)(aHB + oa);
      al[f] = *(const short8*)(aLB + oa);
      bh[f] = *(const short8*)(bHB + ob);
      bl[f] = *(const short8*)(bLB + ob);
    }
    #pragma unroll
    for (int i = 0; i < 4; ++i)
      #pragma unroll
      for (int j = 0; j < 4; ++j) {
        acc[i][j] = __builtin_amdgcn_mfma_f32_16x16x32_bf16(ah[i], bh[j], acc[i][j], 0, 0, 0);
        acc[i][j] = __builtin_amdgcn_mfma_f32_16x16x32_bf16(ah[i], bl[j], acc[i][j], 0, 0, 0);
        acc[i][j] = __builtin_amdgcn_mfma_f32_16x16x32_bf16(al[i], bh[j], acc[i][j], 0, 0, 0);
      }
  }
  #pragma unroll
  for (int i = 0; i < 4; ++i)
    #pragma unroll
    for (int j = 0; j < 4; ++j)
      *(float4*)&red[w * 4096 + (i * 4 + j) * 256 + lane * 4] = *(float4*)&acc[i][j];
  __syncthreads();
  const int vbase = m0 + w * 16 + quad * 4;
  float4 cn = *(const float4*)(cbn + z * VOC + vbase);
  #pragma unroll
  for (int j = 0; j < 4; ++j) {
    float4 s = *(const float4*)&red[(w * 4 + j) * 256 + lane * 4];
    #pragma unroll
    for (int r = 1; r < 4; ++r) {
      float4 tt = *(const float4*)&red[r * 4096 + (w * 4 + j) * 256 + lane * 4];
      s.x += tt.x; s.y += tt.y; s.z += tt.z; s.w += tt.w;
    }
    float o0 = cn.x - 2.f * s.x;
    float o1 = cn.y - 2.f * s.y;
    float o2 = cn.z - 2.f * s.z;
    float o3 = cn.w - 2.f * s.w;
    float bv = o0; int bm = vbase;
    if (o1 < bv) { bv = o1; bm = vbase + 1; }
    if (o2 < bv) { bv = o2; bm = vbase + 2; }
    if (o3 < bv) { bv = o3; bm = vbase + 3; }
    #pragma unroll
    for (int off = 16; off <= 32; off <<= 1) {
      float ov = __shfl_xor(bv, off);
      int om = __shfl_xor(bm, off);
      if (ov < bv || (ov == bv && om < bm)) { bv = ov; bm = om; }
    }
    if (quad == 0) { wv_[w * 64 + j * 16 + l15] = bv; wi_[w * 64 + j * 16 + l15] = bm; }
  }
  __syncthreads();
  if (tid < 64) {
    float bv = wv_[tid]; int bm = wi_[tid];
    #pragma unroll
    for (int g = 1; g < 4; ++g) {
      float ov = wv_[g * 64 + tid]; int om = wi_[g * 64 + tid];
      if (ov < bv || (ov == bv && om < bm)) { bv = ov; bm = om; }
    }
    long prow = (long)z * NN + n0 + tid;
    pval[prow * 16 + blockIdx.x] = bv;
    pidx[prow * 16 + blockIdx.x] = bm;
  }
}

// ---------------- final argmin over the 16 m-chunk partials ----------------
__global__ void k_argmin2(const float* __restrict__ pval, const int* __restrict__ pidx,
                          int* __restrict__ codes) {
  int row = blockIdx.x * 256 + threadIdx.x;   // z*256+n, 3584 total
  if (row >= NCBK * NN) return;
  const float* pv = pval + (long)row * 16;
  const int*   pi = pidx + (long)row * 16;
  float bv = pv[0]; int bm = pi[0];
  #pragma unroll
  for (int c = 1; c < 16; ++c) {
    float v = pv[c]; int m = pi[c];
    if (v < bv || (v == bv && m < bm)) { bv = v; bm = m; }
  }
  codes[row] = bm;
}

// ---------------- gather q as bf16 fragments ----------------
__global__ void k_gather_qbf(const float* __restrict__ cb, const int* __restrict__ codes,
                             ushort* __restrict__ qp) {
  int o = blockIdx.x * 256 + threadIdx.x;
  const int total = NN * C3 / 8;                 // 229376
  if (o >= total) return;
  int frag = o >> 6, r = o & 63;
  int quad = r >> 4, l15 = r & 15;
  int nt = frag / 224, kt = frag - nt * 224;
  int n = nt * 16 + l15;
  int kglob = kt * 32 + quad * 8;
  int kcb = kglob >> 9, d0 = kglob & 511;
  int code = codes[kcb * NN + n];
  const float* s = cb + ((long)(kcb * VOC + code)) * DIMV + d0;
  float4 x0 = *(const float4*)s;
  float4 x1 = *(const float4*)(s + 4);
  uint4 u;
  u.x = (uint)f2bf(x0.x) | ((uint)f2bf(x0.y) << 16);
  u.y = (uint)f2bf(x0.z) | ((uint)f2bf(x0.w) << 16);
  u.z = (uint)f2bf(x1.x) | ((uint)f2bf(x1.y) << 16);
  u.w = (uint)f2bf(x1.z) | ((uint)f2bf(x1.w) << 16);
  ((uint4*)qp)[o] = u;
}

// ---------------- decoder convT GEMM via MFMA bf16 (fragment-packed) ----------------
// 16-wave blocks, disjoint K-1/16 per wave (14 kt), staged 4-round LDS reduce.
__global__ __launch_bounds__(1024) void gemm_a1_mfma(const ushort* __restrict__ dw1p,
    const ushort* __restrict__ qp, float* __restrict__ a1raw) {
  __shared__ __align__(16) float red[4 * 4096];
  const int tid = threadIdx.x;
  const int w = tid >> 6, lane = tid & 63;
  const int l15 = lane & 15, quad = lane >> 4;
  const int mt0 = blockIdx.x * 4, nt0 = blockIdx.y * 4;
  const int kt0 = w * 14;
  f32x4 acc[4][4] = {};
  const ushort* aB = dw1p + ((long)(mt0 * 224 + kt0)) * 512 + lane * 8;
  const ushort* bB = qp   + ((long)(nt0 * 224 + kt0)) * 512 + lane * 8;
  #pragma unroll 2
  for (int kt = 0; kt < 14; ++kt) {
    short8 ah[4], bh[4];
    #pragma unroll
    for (int f = 0; f < 4; ++f) {
      ah[f] = *(const short8*)(aB + ((long)(f * 224 + kt)) * 512);
      bh[f] = *(const short8*)(bB + ((long)(f * 224 + kt)) * 512);
    }
    #pragma unroll
    for (int i = 0; i < 4; ++i)
      #pragma unroll
      for (int j = 0; j < 4; ++j)
        acc[i][j] = __builtin_amdgcn_mfma_f32_16x16x32_bf16(ah[i], bh[j], acc[i][j], 0, 0, 0);
  }
  float4 rsum = make_float4(0.f, 0.f, 0.f, 0.f);
  #pragma unroll
  for (int r = 0; r < 4; ++r) {
    if ((w >> 2) == r) {
      #pragma unroll
      for (int i = 0; i < 4; ++i)
        #pragma unroll
        for (int j = 0; j < 4; ++j)
          *(float4*)&red[(w & 3) * 4096 + (i * 4 + j) * 256 + lane * 4] = *(float4*)&acc[i][j];
    }
    __syncthreads();
    #pragma unroll
    for (int g = 0; g < 4; ++g) {
      float4 t4 = *(const float4*)&red[g * 4096 + w * 256 + lane * 4];
      rsum.x += t4.x; rsum.y += t4.y; rsum.z += t4.z; rsum.w += t4.w;
    }
    __syncthreads();
  }
  const int ci = w >> 2, cj = w & 3;
  const int n = nt0 * 16 + cj * 16 + l15;
  const int mb = mt0 * 16 + ci * 16 + quad * 4;
  float v[4] = {rsum.x, rsum.y, rsum.z, rsum.w};
  #pragma unroll
  for (int reg = 0; reg < 4; ++reg) {
    int m = mb + reg;
    int c = m / 5, jj = m - c * 5;
    a1raw[((long)(n * 5 + jj)) * C2 + c] = v[reg];
  }
}

// ---------------- k_x2: build conv2 im2col X fragment-packed (bf16 hi/lo) -------
__global__ void k_x2(const float* __restrict__ a1raw, const float* __restrict__ ab1g,
                     const float* __restrict__ db1, ushort* __restrict__ Xh,
                     ushort* __restrict__ Xl) {
  int idx = blockIdx.x * 256 + threadIdx.x;
  const int total = 2304 * 2560;
  for (; idx < total; idx += gridDim.x * 256) {
    int grp = idx >> 9;
    int r = idx & 511;
    int e = r & 7, lane = r >> 3;
    int quad = lane >> 4, l15 = lane & 15;
    int nt = grp / 80, kt = grp - nt * 80;
    int nu = nt * 16 + l15;
    int ck = kt * 32 + quad * 8 + e;
    int n = nu / 9, u = nu - n * 9;
    int c = ck / 5, jj = ck - c * 5;
    int w = u + jj;
    int s = n & 127;
    int tc = HOP * s - 6 + w;
    float v;
    if (tc < 0 || tc > TOUT - 1) v = 0.f;
    else if (w >= 4 && w <= 8)
      v = fmaxf(db1[c] + a1raw[((long)(n * 5 + (w - 4))) * C2 + c], 0.f);
    else v = ab1g[c];
    uint bi = __float_as_uint(v);
    Xh[idx] = (ushort)(bi >> 16);
    float rr = v - __uint_as_float(bi & 0xffff0000u);
    Xl[idx] = (ushort)(__float_as_uint(rr) >> 16);
  }
}

// ---------------- decoder conv2 as GEMM: a2act = relu(db2 + dw2 . X^T) ----------
// Fragment-packed operands. 4-wave blocks, disjoint 20 kt per wave,
// barrier-free K-loop, LDS reduce epilogue (proven <=43 us variant).
__global__ __launch_bounds__(256) void gemm_dec2(const ushort* __restrict__ aH,
    const ushort* __restrict__ aL, const ushort* __restrict__ bH,
    const ushort* __restrict__ bL, const float* __restrict__ db2,
    float* __restrict__ a2act) {
  __shared__ __align__(16) float red[4 * 4096];   // 64 KB
  const int tid = threadIdx.x;
  const int w = tid >> 6, lane = tid & 63;
  const int l15 = lane & 15, quad = lane >> 4;
  const int mt0 = blockIdx.x * 4, nt0 = blockIdx.y * 4;
  const int m0 = mt0 * 16, n0 = nt0 * 16;
  const int kt0 = w * 20;                     // disjoint 20 k-tiles per wave
  f32x4 acc[4][4] = {};
  const ushort* aHB = aH + ((long)(mt0 * 80 + kt0)) * 512 + lane * 8;
  const ushort* aLB = aL + ((long)(mt0 * 80 + kt0)) * 512 + lane * 8;
  const ushort* bHB = bH + ((long)(nt0 * 80 + kt0)) * 512 + lane * 8;
  const ushort* bLB = bL + ((long)(nt0 * 80 + kt0)) * 512 + lane * 8;
  for (int kt = 0; kt < 20; ++kt) {
    short8 ah[4], al[4], bh[4], bl[4];
    #pragma unroll
    for (int f = 0; f < 4; ++f) {
      long o = ((long)(f * 80 + kt)) * 512;
      ah[f] = *(const short8*)(aHB + o);
      al[f] = *(const short8*)(aLB + o);
      bh[f] = *(const short8*)(bHB + o);
      bl[f] = *(const short8*)(bLB + o);
    }
    #pragma unroll
    for (int i = 0; i < 4; ++i)
      #pragma unroll
      for (int j = 0; j < 4; ++j) {
        acc[i][j] = __builtin_amdgcn_mfma_f32_16x16x32_bf16(ah[i], bh[j], acc[i][j], 0, 0, 0);
        acc[i][j] = __builtin_amdgcn_mfma_f32_16x16x32_bf16(ah[i], bl[j], acc[i][j], 0, 0, 0);
        acc[i][j] = __builtin_amdgcn_mfma_f32_16x16x32_bf16(al[i], bh[j], acc[i][j], 0, 0, 0);
      }
  }
  #pragma unroll
  for (int i = 0; i < 4; ++i)
    #pragma unroll
    for (int j = 0; j < 4; ++j)
      *(float4*)&red[w * 4096 + (i * 4 + j) * 256 + lane * 4] = *(float4*)&acc[i][j];
  __syncthreads();
  const int mb = m0 + w * 16 + quad * 4;
  float4 bias = *(const float4*)(db2 + mb);
  #pragma unroll
  for (int j = 0; j < 4; ++j) {
    float4 s = *(const float4*)&red[(w * 4 + j) * 256 + lane * 4];
    #pragma unroll
    for (int r = 1; r < 4; ++r) {
      float4 tt = *(const float4*)&red[r * 4096 + (w * 4 + j) * 256 + lane * 4];
      s.x += tt.x; s.y += tt.y; s.z += tt.z; s.w += tt.w;
    }
    const int nu = n0 + j * 16 + l15;
    float4 out;
    out.x = fmaxf(s.x + bias.x, 0.f);
    out.y = fmaxf(s.y + bias.y, 0.f);
    out.z = fmaxf(s.z + bias.z, 0.f);
    out.w = fmaxf(s.w + bias.w, 0.f);
    *(float4*)(a2act + (long)nu * C1 + mb) = out;
  }
}

// ---------------- decoder conv3+tanh + constant fill (merged) ----------------
__global__ __launch_bounds__(256) void k_dec3(const float* __restrict__ a2act,
    const float* __restrict__ ab2g, const float* __restrict__ dw3,
    const float* __restrict__ db3, const float* __restrict__ cconst,
    float* __restrict__ outp) {
  __shared__ float sa2[9 * C1];
  __shared__ float sb[C1];
  int n = blockIdx.x;
  int s = n & 127, b = n >> 7;
  int t = threadIdx.x;
  for (int i = t; i < 9 * C1; i += 256) sa2[i] = a2act[(long)n * 9 * C1 + i];
  sb[t] = ab2g[t];
  __syncthreads();
  float vfill = cconst[0];
  int lo = (s == 0) ? 0 : HOP * s - 384;
  int hi = (s == SS - 1) ? TOUT : HOP * s + 384;
  for (int tc = lo + t; tc < hi; tc += 256) {
    int d = tc - HOP * s;
    if (d < -7 || d > 7) outp[(long)b * TOUT + tc] = vfill;
  }
  int wv = t >> 6, lane = t & 63;
  float b3 = db3[0];
  for (int w15 = wv; w15 < 15; w15 += 4) {
    int tc = HOP * s - 7 + w15;
    if (tc < 0 || tc > TOUT - 1) continue;
    float part = 0.f;
    for (int cc = lane; cc < C1; cc += 64) {
      #pragma unroll
      for (int j = 0; j < 7; ++j) {
        int wcol = tc + j - 3;
        float x;
        if (wcol < 0 || wcol > TOUT - 1) x = 0.f;
        else {
          int du = wcol - (HOP * s - 4);
          x = (du >= 0 && du <= 8) ? sa2[du * C1 + cc] : sb[cc];
        }
        part = fmaf(dw3[cc*7+j], x, part);
      }
    }
    for (int off = 32; off; off >>= 1) part += __shfl_down(part, off);
    if (lane == 0) outp[(long)b * TOUT + tc] = tanhf(part + b3);
  }
}

extern "C" void kernel_launch(void* const* d_in, const int* in_sizes, int n_in,
                              void* d_out, int out_size, void* d_ws, size_t ws_size,
                              hipStream_t stream) {
  const float* audio = (const float*)d_in[0];
  const float* cb    = (const float*)d_in[1];
  const float* ew1   = (const float*)d_in[2];
  const float* eb1   = (const float*)d_in[3];
  const float* ew2   = (const float*)d_in[4];
  const float* eb2   = (const float*)d_in[5];
  const float* ew3   = (const float*)d_in[6];
  const float* eb3   = (const float*)d_in[7];
  const float* dw1   = (const float*)d_in[8];
  const float* db1   = (const float*)d_in[9];
  const float* dw2   = (const float*)d_in[10];
  const float* db2   = (const float*)d_in[11];
  const float* dw3   = (const float*)d_in[12];
  const float* db3   = (const float*)d_in[13];
  float* outp = (float*)d_out;
  float* ws = (float*)d_ws;

  float*  cbn    = ws + OFF_CBN;
  float*  ab1    = ws + OFF_AB1;
  float*  ab2    = ws + OFF_AB2;
  float*  cconst = ws + OFF_CCONST;
  float*  h2c    = ws + OFF_H2C;
  ushort* h2xph  = (ushort*)(ws + OFF_H2XH);
  ushort* h2xpl  = (ushort*)(ws + OFF_H2XL);
  ushort* h3ph   = (ushort*)(ws + OFF_H3H);
  ushort* h3pl   = (ushort*)(ws + OFF_H3L);
  ushort* X1h    = (ushort*)(ws + OFF_X1H);
  ushort* X1l    = (ushort*)(ws + OFF_X1L);
  ushort* cbph   = (ushort*)(ws + OFF_CBPH);
  ushort* cbpl   = (ushort*)(ws + OFF_CBPL);
  ushort* ew3ph  = (ushort*)(ws + OFF_EW3PH);
  ushort* ew3pl  = (ushort*)(ws + OFF_EW3PL);
  ushort* ew2ph  = (ushort*)(ws + OFF_EW2PH);
  ushort* ew2pl  = (ushort*)(ws + OFF_EW2PL);
  float*  pval   = ws + OFF_PVAL;
  int*    pidx   = (int*)(ws + OFF_PIDX);
  ushort* dw1p   = (ushort*)(ws + OFF_DW1P);
  ushort* dw2ph  = (ushort*)(ws + OFF_DW2PH);
  ushort* dw2pl  = (ushort*)(ws + OFF_DW2PL);
  ushort* Xh     = (ushort*)(ws + OFF_XH);
  ushort* Xl     = (ushort*)(ws + OFF_XL);
  int*    codes  = (int*)(ws + OFF_CODES);
  ushort* qp     = (ushort*)(ws + OFF_QBF);
  float*  a1raw  = ws + OFF_A1RAW;
  float*  a2act  = ws + OFF_A2ACT;

  // all weight packs in one BW-saturating launch
  k_packw<<<7360, 256, 0, stream>>>(cb, ew2, ew3, dw2, dw1,
      cbph, cbpl, cbn, ew2ph, ew2pl, ew3ph, ew3pl, dw2ph, dw2pl, dw1p);
  k_prep_ab2<<<C1, 256, 0, stream>>>(db1, dw2, db2, ab1, ab2);
  k_prep_c<<<1, 256, 0, stream>>>(dw3, db3, ab2, cconst);
  k_enc1<<<NN, 256, 0, stream>>>(audio, ew1, eb1, X1h, X1l);
  gemm_enc2<<<dim3(16, 4), 256, 0, stream>>>(ew2ph, ew2pl, X1h, X1l, eb2, h2c);
  k_h2x<<<384, 256, 0, stream>>>(h2c, h2xph, h2xpl);
  gemm_h3<<<448, 256, 0, stream>>>(ew3ph, ew3pl, h2xph, h2xpl, eb3, h3ph, h3pl);
  gemm_scores<<<dim3(16, 4, 14), 256, 0, stream>>>(cbph, cbpl, h3ph, h3pl, cbn, pval, pidx);
  k_argmin2<<<14, 256, 0, stream>>>(pval, pidx, codes);
  k_gather_qbf<<<896, 256, 0, stream>>>(cb, codes, qp);
  gemm_a1_mfma<<<dim3(40, 4), 1024, 0, stream>>>(dw1p, qp, a1raw);
  // Xh/Xl overlap h3p/X1 (dead after gemm_scores) — stream-ordered after gemm_a1
  k_x2<<<4096, 256, 0, stream>>>(a1raw, ab1, db1, Xh, Xl);
  gemm_dec2<<<dim3(4, 36), 256, 0, stream>>>(dw2ph, dw2pl, Xh, Xl, db2, a2act);
  k_dec3<<<NN, 256, 0, stream>>>(a2act, ab2, dw3, db3, cconst, outp);
}